// Round 5
// baseline (800.973 us; speedup 1.0000x reference)
//
#include <hip/hip_runtime.h>
#include <math.h>

// ---------------------------------------------------------------------------
// GCN 5-layer forward, dinv-prescaled formulation.
//   agg[v] = dinv[v] * ( sum_{s in N(v)} hs[s] + hs[v] ),  hs = dinv (.) h.
// Layer plan (narrow-side aggregation):
//   L1: agg2(xs=dinv*x) -> gemm 2->128 +b1 relu *dinv
//   L2: gemm 128->128 (cm32 out) ; agg128xp2 +b2 relu *dinv (cm32)
//   L3: gemm 128->32 (cm32 in) ; agg32 +b3 relu *dinv
//   L4: gemm 32->32   ; agg32  +b4 relu *dinv
//   L5: agg32 raw     ; gemm_final: (t5@W5+b5).relu @ Wl + bl -> out
// R18: persistent QUARTILE-phase agg128xp2, spill-fixed.
//   R17 post-mortem: launch_bounds(256,6) capped VGPR at 85; acc[9]+buffers
//   needed ~90 -> accumulators spilled to scratch (VGPR_Count=40, WRITE
//   50->92MB, FETCH +42MB, BW 2.3TB/s). The schedule idea was never tested.
//   Fix: launch_bounds(256,4) (128 VGPR budget), NG=13 acc (52 regs, est
//   ~100 total), grid 968 <= 1024 co-resident; quartile segments (avg 4
//   edges, 2x MLP vs octile); capped soft phase barrier (atomic arrive +
//   spin, 20K cap) hard-aligns phases; performance-only, deadlock-free.
//   Per-XCD per-phase gather ws = 3.2MB (L2-resident). Predicted FETCH
//   327->~180MB, dur 98->~55-75us, WRITE back to 50MB.
// R16 post-mortem (NULL): src-quartile edge order with unchanged agg ->
//   FETCH identical. Order without schedule does nothing (deg~16 = one
//   burst; 256 short blocks/XCD mix all phases).
// R15 post-mortem (REVERTED): 8-col chunks on latency-bound agg32 trio:
//   4x instruction stream for fewer bytes = loss.
// R14 post-mortem: agg128x (cm32, 8 XCD classes) 127->98us, FETCH 414->328.
//   12.8MB slice >> 4MB L2 caps hit ~63%.
// Structural walls (measured): fill/count atomic floors; fp32 vector-ALU
//   gemms (no fp32 MFMA; bf16 blows the 7.9e-5 absmax budget).
// ---------------------------------------------------------------------------

static inline int cdiv(int a, int b) { return (a + b - 1) / b; }

__global__ void zero_i32(int* __restrict__ p, int n) {
    int i = blockIdx.x * 256 + threadIdx.x;
    if (i < n) p[i] = 0;
}

// Degree count per (dst, src-quartile): atomics into cntq[4N].
__global__ void count_q(const int* __restrict__ src, const int* __restrict__ dst,
                        int* __restrict__ cntq, int E, int q1) {
    int e = blockIdx.x * 256 + threadIdx.x;
    if (e < E) {
        int s = src[e];
        int q = (s >= q1) + (s >= 2 * q1) + (s >= 3 * q1);
        atomicAdd(&cntq[dst[e] * 4 + q], 1);
    }
}

// Inclusive scan per 256-block of per-node TOTALS (sum of 4 quartile counts);
// inclusive partials to off, block totals to bsum.
__global__ void scan1q(const int* __restrict__ cntq, int* __restrict__ off,
                       int* __restrict__ bsum, int n) {
    __shared__ int sm[256];
    int i = blockIdx.x * 256 + threadIdx.x;
    int v = 0;
    if (i < n) {
        int4 c = *reinterpret_cast<const int4*>(cntq + 4 * (size_t)i);
        v = c.x + c.y + c.z + c.w;
    }
    sm[threadIdx.x] = v;
    __syncthreads();
    for (int ofs = 1; ofs < 256; ofs <<= 1) {
        int t = (threadIdx.x >= (unsigned)ofs) ? sm[threadIdx.x - ofs] : 0;
        __syncthreads();
        sm[threadIdx.x] += t;
        __syncthreads();
    }
    if (i < n) off[i] = sm[threadIdx.x];
    if (threadIdx.x == 255) bsum[blockIdx.x] = sm[255];
}

// Exclusive scan of block sums (nb <= 512).
__global__ void scan2(const int* __restrict__ bsum, int* __restrict__ bpre,
                      int nb, int* __restrict__ off, int N, int E) {
    __shared__ int sm[512];
    int t = threadIdx.x;
    sm[t] = (t < nb) ? bsum[t] : 0;
    __syncthreads();
    for (int ofs = 1; ofs < 512; ofs <<= 1) {
        int v = (t >= ofs) ? sm[t - ofs] : 0;
        __syncthreads();
        sm[t] += v;
        __syncthreads();
    }
    if (t < nb) bpre[t] = sm[t] - bsum[t];
    if (t == 0) off[N] = E;
}

// Fused: finalize off (exclusive), seed 4 quartile cursors per node (seg
// starts; post-fill they hold seg ENDS), dinv=1/sqrt(deg+1), xs = dinv * x.
__global__ void scan3_fused(const int* __restrict__ cntq, const int* __restrict__ bpre,
                            int* __restrict__ off, int* __restrict__ cursorq,
                            const float* __restrict__ x, float* __restrict__ dinv,
                            float* __restrict__ xs, int n) {
    int i = blockIdx.x * 256 + threadIdx.x;
    if (i < n) {
        int4 cq = *reinterpret_cast<const int4*>(cntq + 4 * (size_t)i);
        int c = cq.x + cq.y + cq.z + cq.w;
        int o = off[i] - c + bpre[blockIdx.x];
        off[i] = o;
        int4 cur;
        cur.x = o;
        cur.y = o + cq.x;
        cur.z = o + cq.x + cq.y;
        cur.w = o + cq.x + cq.y + cq.z;
        *reinterpret_cast<int4*>(cursorq + 4 * (size_t)i) = cur;
        float dv = 1.0f / sqrtf((float)c + 1.0f);
        dinv[i] = dv;
        float2 xv = *reinterpret_cast<const float2*>(x + 2 * (size_t)i);
        *reinterpret_cast<float2*>(xs + 2 * (size_t)i) = float2{dv * xv.x, dv * xv.y};
    }
}

// XCD-class-filtered CSR fill with src-quartile bucketing: class c handles
// only its dst-range (cursorq slice ~200KB, csr slice ~800KB stay in one
// XCD's L2). Each node's edge list lands as [q0|q1|q2|q3] segments.
__global__ __launch_bounds__(256) void fill_ranged(const int* __restrict__ src,
                                                   const int* __restrict__ dst,
                                                   int* __restrict__ cursorq,
                                                   int* __restrict__ csr,
                                                   int E, int N, int echunk, int q1) {
    int cls = blockIdx.x & 7;
    int chunk = blockIdx.x >> 3;
    int per = (N + 7) >> 3;
    int lo = cls * per;
    int hi = lo + per; if (hi > N) hi = N;
    int e0 = chunk * echunk;
    int e1 = e0 + echunk; if (e1 > E) e1 = E;
    for (int e = e0 + (int)threadIdx.x; e < e1; e += 256) {
        int d = dst[e];
        if (d >= lo && d < hi) {
            int s = src[e];
            int q = (s >= q1) + (s >= 2 * q1) + (s >= 3 * q1);
            int p = atomicAdd(&cursorq[d * 4 + q], 1);
            csr[p] = s;
        }
    }
}

// ---------------------------------------------------------------------------
// Aggregation of pre-scaled [N,2] input: one thread per node.
// ---------------------------------------------------------------------------
__global__ __launch_bounds__(256) void agg2_kernel(const float* __restrict__ xs,
                                                   const int* __restrict__ off,
                                                   const int* __restrict__ csr,
                                                   const float* __restrict__ dinv,
                                                   float* __restrict__ out, int n) {
    int v = blockIdx.x * 256 + threadIdx.x;
    if (v >= n) return;
    float a0 = 0.f, a1 = 0.f;
    int e0 = off[v], e1 = off[v + 1];
    for (int e = e0; e < e1; e++) {
        int s = csr[e];
        float2 q = *reinterpret_cast<const float2*>(xs + 2 * (size_t)s);
        a0 += q.x;
        a1 += q.y;
    }
    float dv = dinv[v];
    float2 xv = *reinterpret_cast<const float2*>(xs + 2 * (size_t)v);
    *reinterpret_cast<float2*>(out + 2 * (size_t)v) =
        float2{dv * (a0 + xv.x), dv * (a1 + xv.y)};
}

// ---------------------------------------------------------------------------
// agg128xp2: F=128 aggregation, XCD-sliced AND quartile-phase-aligned.
// h chunk-major hc[4][N][32]; class = blockIdx&7 = (chunk, dst-half).
// Persistent co-resident grid (968 blocks <= 4/CU x 256CU), each block owns
// NG*32 = 416 nodes (acc[NG] in VGPRs, fully unrolled = statically indexed),
// sweeps 4 src-quartile phases OUTERMOST over quartile-bucketed csr
// segments. Capped soft barrier between phases hard-aligns the sweep ->
// per-XCD per-phase gather ws = 3.2MB (L2-resident). Barrier is
// performance-only: timeout/progress cannot affect correctness.
// Seg bounds: start = (q==0 ? off[v] : cur4[v*4+q-1]), end = cur4[v*4+q].
// ---------------------------------------------------------------------------
template <bool BR, bool PS, int NG>
__global__ __launch_bounds__(256, 4) void agg128xp2_kernel(const float* __restrict__ hc,
                                                           const int* __restrict__ off,
                                                           const int* __restrict__ cur4,
                                                           const int* __restrict__ csr,
                                                           const float* __restrict__ dinv,
                                                           const float* __restrict__ bias,
                                                           float* __restrict__ outc,
                                                           int* __restrict__ bar, int n) {
    int cls = blockIdx.x & 7;
    int chunk = cls >> 1;
    int half = cls & 1;
    int n2 = (n + 1) >> 1;
    int lo = half * n2;
    int hi = lo + n2; if (hi > n) hi = n;

    const float* __restrict__ h = hc + (size_t)chunk * n * 32;
    float* __restrict__ out = outc + (size_t)chunk * n * 32;

    int tid = threadIdx.x;
    int lane = tid & 63;
    int sl = lane & 7;
    int subbase = lane & ~7;
    int grpid = tid >> 3;                 // 0..31
    int nstart = lo + (blockIdx.x >> 3) * (NG * 32);
    int nblocks = (int)gridDim.x;

    float4 acc[NG];
#pragma unroll
    for (int g = 0; g < NG; g++) acc[g] = float4{0.f, 0.f, 0.f, 0.f};

#pragma unroll 1
    for (int q = 0; q < 4; q++) {
        if (q > 0) {
            // Capped soft phase barrier (performance-only; deadlock-free).
            if (tid == 0) {
                atomicAdd(&bar[q], 1);
                volatile int* vb = bar + q;
                int it = 0;
                while (*vb < nblocks && it < 20000) {
                    __builtin_amdgcn_s_sleep(2);
                    ++it;
                }
            }
            __syncthreads();
        }
#pragma unroll
        for (int g = 0; g < NG; g++) {
            int v = nstart + g * 32 + grpid;
            if (v >= hi) continue;
            int s0 = (q == 0) ? off[v] : cur4[v * 4 + q - 1];
            int s1 = cur4[v * 4 + q];
            for (int base = s0; base < s1; base += 8) {
                int m = s1 - base; if (m > 8) m = 8;
                int idx = (sl < m) ? csr[base + sl] : 0;
                // first half: lanes subbase+0..3
                int mA = (m < 4) ? m : 4;
                if (mA == 4) {
                    float4 hb[4];
#pragma unroll
                    for (int u = 0; u < 4; u++) {
                        int s = __shfl(idx, subbase + u);
                        hb[u] = *reinterpret_cast<const float4*>(h + (size_t)s * 32 + sl * 4);
                    }
#pragma unroll
                    for (int u = 0; u < 4; u++) {
                        acc[g].x += hb[u].x; acc[g].y += hb[u].y;
                        acc[g].z += hb[u].z; acc[g].w += hb[u].w;
                    }
                } else {
                    int i = 0;
                    if (i + 2 <= mA) {
                        int sa = __shfl(idx, subbase + i);
                        int sb = __shfl(idx, subbase + i + 1);
                        float4 h0 = *reinterpret_cast<const float4*>(h + (size_t)sa * 32 + sl * 4);
                        float4 h1 = *reinterpret_cast<const float4*>(h + (size_t)sb * 32 + sl * 4);
                        acc[g].x += h0.x + h1.x; acc[g].y += h0.y + h1.y;
                        acc[g].z += h0.z + h1.z; acc[g].w += h0.w + h1.w;
                        i += 2;
                    }
                    if (i < mA) {
                        int sa = __shfl(idx, subbase + i);
                        float4 h0 = *reinterpret_cast<const float4*>(h + (size_t)sa * 32 + sl * 4);
                        acc[g].x += h0.x; acc[g].y += h0.y;
                        acc[g].z += h0.z; acc[g].w += h0.w;
                    }
                }
                // second half: lanes subbase+4..7
                if (m > 4) {
                    int mB = m - 4;
                    if (mB == 4) {
                        float4 hb[4];
#pragma unroll
                        for (int u = 0; u < 4; u++) {
                            int s = __shfl(idx, subbase + 4 + u);
                            hb[u] = *reinterpret_cast<const float4*>(h + (size_t)s * 32 + sl * 4);
                        }
#pragma unroll
                        for (int u = 0; u < 4; u++) {
                            acc[g].x += hb[u].x; acc[g].y += hb[u].y;
                            acc[g].z += hb[u].z; acc[g].w += hb[u].w;
                        }
                    } else {
                        int j = 0;
                        if (j + 2 <= mB) {
                            int sa = __shfl(idx, subbase + 4 + j);
                            int sb = __shfl(idx, subbase + 4 + j + 1);
                            float4 h0 = *reinterpret_cast<const float4*>(h + (size_t)sa * 32 + sl * 4);
                            float4 h1 = *reinterpret_cast<const float4*>(h + (size_t)sb * 32 + sl * 4);
                            acc[g].x += h0.x + h1.x; acc[g].y += h0.y + h1.y;
                            acc[g].z += h0.z + h1.z; acc[g].w += h0.w + h1.w;
                            j += 2;
                        }
                        if (j < mB) {
                            int sa = __shfl(idx, subbase + 4 + j);
                            float4 h0 = *reinterpret_cast<const float4*>(h + (size_t)sa * 32 + sl * 4);
                            acc[g].x += h0.x; acc[g].y += h0.y;
                            acc[g].z += h0.z; acc[g].w += h0.w;
                        }
                    }
                }
            }
        }
    }

    // Epilogue: self-loop + bias/relu + post-scale, per owned node.
#pragma unroll
    for (int g = 0; g < NG; g++) {
        int v = nstart + g * 32 + grpid;
        if (v >= hi) continue;
        float dv = dinv[v];
        float4 hv = *reinterpret_cast<const float4*>(h + (size_t)v * 32 + sl * 4);
        float o0 = dv * (acc[g].x + hv.x);
        float o1 = dv * (acc[g].y + hv.y);
        float o2 = dv * (acc[g].z + hv.z);
        float o3 = dv * (acc[g].w + hv.w);
        if constexpr (BR) {
            float4 b = *reinterpret_cast<const float4*>(bias + chunk * 32 + sl * 4);
            o0 = fmaxf(o0 + b.x, 0.f);
            o1 = fmaxf(o1 + b.y, 0.f);
            o2 = fmaxf(o2 + b.z, 0.f);
            o3 = fmaxf(o3 + b.w, 0.f);
        }
        if constexpr (PS) {
            o0 *= dv; o1 *= dv; o2 *= dv; o3 *= dv;
        }
        *reinterpret_cast<float4*>(out + (size_t)v * 32 + sl * 4) = float4{o0, o1, o2, o3};
    }
}

// ---------------------------------------------------------------------------
// agg32: F=32, 8 lanes/node, lane owns 4 cols (float4). Dual 8-edge chunks.
// (Quartile edge order is transparent here: list walked in csr order.)
// ---------------------------------------------------------------------------
template <bool BR, bool PS>
__global__ __launch_bounds__(256) void agg32_kernel(const float* __restrict__ h,
                                                    const int* __restrict__ off,
                                                    const int* __restrict__ csr,
                                                    const float* __restrict__ dinv,
                                                    const float* __restrict__ bias,
                                                    float* __restrict__ out, int n) {
    int tid = threadIdx.x;
    int lane = tid & 63;
    int sl = lane & 7;
    int subbase = lane & ~7;
    int wave = tid >> 6;
    int v = blockIdx.x * 32 + wave * 8 + (lane >> 3);
    if (v >= n) return;

    int start = off[v];
    int end = off[v + 1];

    float4 acc = {0.f, 0.f, 0.f, 0.f};

    for (int base = start; base < end; base += 16) {
        int m = end - base;
        if (m > 16) m = 16;
        int idxA = (sl < m) ? csr[base + sl] : 0;
        int idxB = (8 + sl < m) ? csr[base + 8 + sl] : 0;
        if (m == 16) {
            float4 hb[16];
#pragma unroll
            for (int u = 0; u < 16; u++) {
                int s = __shfl((u < 8) ? idxA : idxB, subbase + (u & 7));
                hb[u] = *reinterpret_cast<const float4*>(h + (size_t)s * 32 + sl * 4);
            }
#pragma unroll
            for (int u = 0; u < 16; u++) {
                acc.x += hb[u].x; acc.y += hb[u].y; acc.z += hb[u].z; acc.w += hb[u].w;
            }
        } else {
            int ma = (m < 8) ? m : 8;
            int i = 0;
            for (; i + 4 <= ma; i += 4) {
                float4 hb[4];
#pragma unroll
                for (int u = 0; u < 4; u++) {
                    int s = __shfl(idxA, subbase + i + u);
                    hb[u] = *reinterpret_cast<const float4*>(h + (size_t)s * 32 + sl * 4);
                }
#pragma unroll
                for (int u = 0; u < 4; u++) {
                    acc.x += hb[u].x; acc.y += hb[u].y; acc.z += hb[u].z; acc.w += hb[u].w;
                }
            }
            if (i + 2 <= ma) {
                int s0 = __shfl(idxA, subbase + i);
                int s1 = __shfl(idxA, subbase + i + 1);
                float4 h0 = *reinterpret_cast<const float4*>(h + (size_t)s0 * 32 + sl * 4);
                float4 h1 = *reinterpret_cast<const float4*>(h + (size_t)s1 * 32 + sl * 4);
                acc.x += h0.x + h1.x; acc.y += h0.y + h1.y;
                acc.z += h0.z + h1.z; acc.w += h0.w + h1.w;
                i += 2;
            }
            if (i < ma) {
                int s0 = __shfl(idxA, subbase + i);
                float4 h0 = *reinterpret_cast<const float4*>(h + (size_t)s0 * 32 + sl * 4);
                acc.x += h0.x; acc.y += h0.y; acc.z += h0.z; acc.w += h0.w;
            }
            if (m > 8) {
                int mb = m - 8;
                int j = 0;
                for (; j + 4 <= mb; j += 4) {
                    float4 hb[4];
#pragma unroll
                    for (int u = 0; u < 4; u++) {
                        int s = __shfl(idxB, subbase + j + u);
                        hb[u] = *reinterpret_cast<const float4*>(h + (size_t)s * 32 + sl * 4);
                    }
#pragma unroll
                    for (int u = 0; u < 4; u++) {
                        acc.x += hb[u].x; acc.y += hb[u].y; acc.z += hb[u].z; acc.w += hb[u].w;
                    }
                }
                if (j + 2 <= mb) {
                    int s0 = __shfl(idxB, subbase + j);
                    int s1 = __shfl(idxB, subbase + j + 1);
                    float4 h0 = *reinterpret_cast<const float4*>(h + (size_t)s0 * 32 + sl * 4);
                    float4 h1 = *reinterpret_cast<const float4*>(h + (size_t)s1 * 32 + sl * 4);
                    acc.x += h0.x + h1.x; acc.y += h0.y + h1.y;
                    acc.z += h0.z + h1.z; acc.w += h0.w + h1.w;
                    j += 2;
                }
                if (j < mb) {
                    int s0 = __shfl(idxB, subbase + j);
                    float4 h0 = *reinterpret_cast<const float4*>(h + (size_t)s0 * 32 + sl * 4);
                    acc.x += h0.x; acc.y += h0.y; acc.z += h0.z; acc.w += h0.w;
                }
            }
        }
    }

    float dv = dinv[v];
    float4 hv = *reinterpret_cast<const float4*>(h + (size_t)v * 32 + sl * 4);
    float o0 = dv * (acc.x + hv.x);
    float o1 = dv * (acc.y + hv.y);
    float o2 = dv * (acc.z + hv.z);
    float o3 = dv * (acc.w + hv.w);
    if constexpr (BR) {
        float4 b = *reinterpret_cast<const float4*>(bias + sl * 4);
        o0 = fmaxf(o0 + b.x, 0.f);
        o1 = fmaxf(o1 + b.y, 0.f);
        o2 = fmaxf(o2 + b.z, 0.f);
        o3 = fmaxf(o3 + b.w, 0.f);
    }
    if constexpr (PS) {
        o0 *= dv; o1 *= dv; o2 *= dv; o3 *= dv;
    }
    *reinterpret_cast<float4*>(out + (size_t)v * 32 + sl * 4) = float4{o0, o1, o2, o3};
}

// ---------------------------------------------------------------------------
// Register-tiled GEMM: h[N,F] = x[N,K] @ W[K,F]; epilogue +bias/relu (BR),
// *dinv[row] (PS). KC=32 (KCP=36 breaks pow-2 banks): K=128 -> 4 chunks,
// K=32 -> single chunk (2 barriers).
// CIN/COUT: 0 = row-major, 32 = chunk-major [F/32][N][32] (for agg128xp2).
// ---------------------------------------------------------------------------
template <int K, int F, bool BR, bool PS, int CIN = 0, int COUT = 0>
__global__ __launch_bounds__(256, 4) void gemm_tiled(const float* __restrict__ x,
                                                     const float* __restrict__ W,
                                                     const float* __restrict__ bias,
                                                     const float* __restrict__ dinv,
                                                     float* __restrict__ h, int n) {
    constexpr int KC = 32;
    constexpr int KCP = 36;             // padded row stride (144 B, 16B-aligned)
    constexpr int ROWS = 64;
    constexpr int TPC = F / 4;
    constexpr int RT = 256 / TPC;
    constexpr int RPT = ROWS / RT;
    static_assert(K % KC == 0, "K must be a multiple of 32");

    __shared__ float Ws[KC * F];
    __shared__ float Xs[ROWS * KCP];

    const int tid = threadIdx.x;
    const int cb = (tid % TPC) * 4;
    const int tr = tid / TPC;
    const int row0 = blockIdx.x * ROWS;

    float acc[RPT][4];
#pragma unroll
    for (int r = 0; r < RPT; r++)
#pragma unroll
        for (int j = 0; j < 4; j++) acc[r][j] = 0.f;

#pragma unroll 1
    for (int k0 = 0; k0 < K; k0 += KC) {
        __syncthreads();
        {
            // Stage x chunk: 64 rows x 32 cols; thread -> row tid>>2, 8 cols.
            int r = tid >> 2;
            int kk = (tid & 3) * 8;
            int gr = row0 + r;
            float4 v0 = {0.f, 0.f, 0.f, 0.f}, v1 = {0.f, 0.f, 0.f, 0.f};
            if (gr < n) {
                if constexpr (CIN == 32) {
                    const float* xb = x + (size_t)(k0 >> 5) * n * 32 + (size_t)gr * 32 + kk;
                    v0 = *reinterpret_cast<const float4*>(xb);
                    v1 = *reinterpret_cast<const float4*>(xb + 4);
                } else {
                    v0 = *reinterpret_cast<const float4*>(x + (size_t)gr * K + k0 + kk);
                    v1 = *reinterpret_cast<const float4*>(x + (size_t)gr * K + k0 + kk + 4);
                }
            }
            *reinterpret_cast<float4*>(&Xs[r * KCP + kk]) = v0;
            *reinterpret_cast<float4*>(&Xs[r * KCP + kk + 4]) = v1;
        }
        for (int i = tid; i < KC * F / 4; i += 256) {
            *reinterpret_cast<float4*>(&Ws[i * 4]) =
                *reinterpret_cast<const float4*>(W + (size_t)k0 * F + i * 4);
        }
        __syncthreads();

#pragma unroll 4
        for (int kk4 = 0; kk4 < KC; kk4 += 4) {
            float4 xr[RPT];
#pragma unroll
            for (int r = 0; r < RPT; r++)
                xr[r] = *reinterpret_cast<const float4*>(&Xs[(tr * RPT + r) * KCP + kk4]);
#pragma unroll
            for (int j = 0; j < 4; j++) {
                float4 w = *reinterpret_cast<const float4*>(&Ws[(kk4 + j) * F + cb]);
#pragma unroll
                for (int r = 0; r < RPT; r++) {
                    float xv = (j == 0) ? xr[r].x : (j == 1) ? xr[r].y
                             : (j == 2) ? xr[r].z : xr[r].w;
                    acc[r][0] += xv * w.x;
                    acc[r][1] += xv * w.y;
                    acc[r][2] += xv * w.z;
                    acc[r][3] += xv * w.w;
                }
            }
        }
    }

    float4 b = float4{0.f, 0.f, 0.f, 0.f};
    if constexpr (BR) b = *reinterpret_cast<const float4*>(bias + cb);
#pragma unroll
    for (int r = 0; r < RPT; r++) {
        int row = row0 + tr * RPT + r;
        if (row < n) {
            float o0 = acc[r][0], o1 = acc[r][1], o2 = acc[r][2], o3 = acc[r][3];
            if constexpr (BR) {
                o0 = fmaxf(o0 + b.x, 0.f);
                o1 = fmaxf(o1 + b.y, 0.f);
                o2 = fmaxf(o2 + b.z, 0.f);
                o3 = fmaxf(o3 + b.w, 0.f);
            }
            if constexpr (PS) {
                float dv = dinv[row];
                o0 *= dv; o1 *= dv; o2 *= dv; o3 *= dv;
            }
            if constexpr (COUT == 32) {
                float* hb = h + (size_t)(cb >> 5) * n * 32 + (size_t)row * 32 + (cb & 31);
                *reinterpret_cast<float4*>(hb) = float4{o0, o1, o2, o3};
            } else {
                *reinterpret_cast<float4*>(&h[(size_t)row * F + cb]) = float4{o0, o1, o2, o3};
            }
        }
    }
}

// ---------------------------------------------------------------------------
// Fused L5 + final: out[v] = relu(t5[v]@W5 + b5) . Wl + bl.  K=32, F=64.
// Single KC=32 chunk; row outputs in 16 lanes x 4 regs -> dot with Wl (LDS)
// then 4-step shfl-xor reduce; lane0-of-16 writes out[row].
// ---------------------------------------------------------------------------
__global__ __launch_bounds__(256, 4) void gemm_final(const float* __restrict__ x,
                                                     const float* __restrict__ W,
                                                     const float* __restrict__ bias,
                                                     const float* __restrict__ Wl,
                                                     const float* __restrict__ bl,
                                                     float* __restrict__ out, int n) {
    constexpr int K = 32, F = 64;
    constexpr int KC = 32;
    constexpr int KCP = 36;
    constexpr int ROWS = 64;
    constexpr int TPC = F / 4;          // 16
    constexpr int RT = 256 / TPC;       // 16
    constexpr int RPT = ROWS / RT;      // 4

    __shared__ float Ws[KC * F];
    __shared__ float Xs[ROWS * KCP];
    __shared__ float wl[F];

    const int tid = threadIdx.x;
    if (tid < F) wl[tid] = Wl[tid];
    const int cb = (tid % TPC) * 4;
    const int tr = tid / TPC;
    const int row0 = blockIdx.x * ROWS;

    float acc[RPT][4];
#pragma unroll
    for (int r = 0; r < RPT; r++)
#pragma unroll
        for (int j = 0; j < 4; j++) acc[r][j] = 0.f;

    {
        {
            int r = tid >> 2;
            int kk = (tid & 3) * 8;
            int gr = row0 + r;
            float4 v0 = {0.f, 0.f, 0.f, 0.f}, v1 = {0.f, 0.f, 0.f, 0.f};
            if (gr < n) {
                v0 = *reinterpret_cast<const float4*>(x + (size_t)gr * K + kk);
                v1 = *reinterpret_cast<const float4*>(x + (size_t)gr * K + kk + 4);
            }
            *reinterpret_cast<float4*>(&Xs[r * KCP + kk]) = v0;
            *reinterpret_cast<float4*>(&Xs[r * KCP + kk + 4]) = v1;
        }
        for (int i = tid; i < KC * F / 4; i += 256) {
            *reinterpret_cast<float4*>(&Ws[i * 4]) =
                *reinterpret_cast<const float4*>(W + i * 4);
        }
        __syncthreads();

#pragma unroll 4
        for (int kk4 = 0; kk4 < KC; kk4 += 4) {
            float4 xr[RPT];
#pragma unroll
            for (int r = 0; r < RPT; r++)
                xr[r] = *reinterpret_cast<const float4*>(&Xs[(tr * RPT + r) * KCP + kk4]);
#pragma unroll
            for (int j = 0; j < 4; j++) {
                float4 w = *reinterpret_cast<const float4*>(&Ws[(kk4 + j) * F + cb]);
#pragma unroll
                for (int r = 0; r < RPT; r++) {
                    float xv = (j == 0) ? xr[r].x : (j == 1) ? xr[r].y
                             : (j == 2) ? xr[r].z : xr[r].w;
                    acc[r][0] += xv * w.x;
                    acc[r][1] += xv * w.y;
                    acc[r][2] += xv * w.z;
                    acc[r][3] += xv * w.w;
                }
            }
        }
    }

    float4 b = *reinterpret_cast<const float4*>(bias + cb);
    float4 w = *reinterpret_cast<const float4*>(&wl[cb]);
    float blv = bl[0];
#pragma unroll
    for (int r = 0; r < RPT; r++) {
        int row = row0 + tr * RPT + r;
        float o0 = fmaxf(acc[r][0] + b.x, 0.f);
        float o1 = fmaxf(acc[r][1] + b.y, 0.f);
        float o2 = fmaxf(acc[r][2] + b.z, 0.f);
        float o3 = fmaxf(acc[r][3] + b.w, 0.f);
        float partial = o0 * w.x + o1 * w.y + o2 * w.z + o3 * w.w;
        partial += __shfl_xor(partial, 8, 16);
        partial += __shfl_xor(partial, 4, 16);
        partial += __shfl_xor(partial, 2, 16);
        partial += __shfl_xor(partial, 1, 16);
        if ((tid & 15) == 0 && row < n) out[row] = partial + blv;
    }
}

// Simple GEMM for K=2 (layer 1), epilogue +bias/relu (BR), *dinv (PS).
template <int K, int F, bool BR, bool PS>
__global__ __launch_bounds__(256, 4) void gemm_small(const float* __restrict__ x,
                                                     const float* __restrict__ W,
                                                     const float* __restrict__ bias,
                                                     const float* __restrict__ dinv,
                                                     float* __restrict__ h, int n) {
    constexpr int TPR = F / 4;
    constexpr int ROWS = 256 / TPR;
    __shared__ float Ws[K * F];
    for (int i = threadIdx.x; i < K * F; i += 256) Ws[i] = W[i];
    __syncthreads();

    int tid = threadIdx.x;
    int cb = (tid % TPR) * 4;
    int r = blockIdx.x * ROWS + tid / TPR;
    if (r >= n) return;

    const float* xr = x + (size_t)r * K;
    float a0 = 0.f, a1 = 0.f, a2 = 0.f, a3 = 0.f;
#pragma unroll
    for (int k = 0; k < K; k++) {
        float xv = xr[k];
        float4 w = *reinterpret_cast<const float4*>(&Ws[k * F + cb]);
        a0 += xv * w.x; a1 += xv * w.y; a2 += xv * w.z; a3 += xv * w.w;
    }
    if constexpr (BR) {
        float4 b = *reinterpret_cast<const float4*>(bias + cb);
        a0 = fmaxf(a0 + b.x, 0.f);
        a1 = fmaxf(a1 + b.y, 0.f);
        a2 = fmaxf(a2 + b.z, 0.f);
        a3 = fmaxf(a3 + b.w, 0.f);
    }
    if constexpr (PS) {
        float dv = dinv[r];
        a0 *= dv; a1 *= dv; a2 *= dv; a3 *= dv;
    }
    *reinterpret_cast<float4*>(&h[(size_t)r * K * 0 + (size_t)r * F + cb]) = float4{a0, a1, a2, a3};
}

extern "C" void kernel_launch(void* const* d_in, const int* in_sizes, int n_in,
                              void* d_out, int out_size, void* d_ws, size_t ws_size,
                              hipStream_t stream) {
    const float* x = (const float*)d_in[0];
    const int* ei = (const int*)d_in[1];
    const float* W1 = (const float*)d_in[3];
    const float* b1 = (const float*)d_in[4];
    const float* W2 = (const float*)d_in[5];
    const float* b2 = (const float*)d_in[6];
    const float* W3 = (const float*)d_in[7];
    const float* b3 = (const float*)d_in[8];
    const float* W4 = (const float*)d_in[9];
    const float* b4 = (const float*)d_in[10];
    const float* W5 = (const float*)d_in[11];
    const float* b5 = (const float*)d_in[12];
    const float* Wl = (const float*)d_in[13];
    const float* bl = (const float*)d_in[14];

    const int N = in_sizes[0] / 2;
    const int E = in_sizes[1] / 2;
    const int* src = ei;
    const int* dst = ei + E;

    char* wp = (char*)d_ws;
    auto alloc = [&](size_t bytes) -> void* {
        void* p = wp;
        wp += ((bytes + 255) / 256) * 256;
        return p;
    };
    int* cntq = (int*)alloc((size_t)N * 4 * 4);
    int* off = (int*)alloc((size_t)(N + 1) * 4);
    int* cursorq = (int*)alloc((size_t)N * 4 * 4);
    int* bsum = (int*)alloc(512 * 4);
    int* bpre = (int*)alloc(512 * 4);
    int* bar = (int*)alloc(64 * 4);
    int* csr = (int*)alloc((size_t)E * 4);
    float* dinv = (float*)alloc((size_t)N * 4);
    float* xs2 = (float*)alloc((size_t)N * 2 * 4);
    float* t2 = (float*)alloc((size_t)N * 2 * 4);
    float* bufA = (float*)alloc((size_t)N * 128 * 4);
    float* bufB = (float*)alloc((size_t)N * 128 * 4);

    const int gN = cdiv(N, 256);
    const int gE = cdiv(E, 256);
    const int nb = gN;
    const int gT = cdiv(N, 64);
    const int q1 = (N + 3) / 4;         // src quartile width

    // Ranged fill grid: 8 classes x 128 chunks.
    const int NCHUNK = 128;
    const int echunk = cdiv(E, NCHUNK);
    const int gR = 8 * NCHUNK;

    // agg128xp2 persistent grid: 8 classes x BPC blocks, all co-resident
    // (416 nodes/block in VGPR acc; 256CU x 4 blocks/CU capacity = 1024).
    constexpr int NG = 13;              // node-groups per 8-lane slot
    const int BPC = cdiv((N + 1) / 2, NG * 32);
    const int gP = 8 * BPC;

    // --- CSR build (src-quartile-bucketed edge order) ---
    zero_i32<<<cdiv(4 * N, 256), 256, 0, stream>>>(cntq, 4 * N);
    zero_i32<<<1, 256, 0, stream>>>(bar, 64);
    count_q<<<gE, 256, 0, stream>>>(src, dst, cntq, E, q1);
    scan1q<<<nb, 256, 0, stream>>>(cntq, off, bsum, N);
    scan2<<<1, 512, 0, stream>>>(bsum, bpre, nb, off, N, E);
    scan3_fused<<<nb, 256, 0, stream>>>(cntq, bpre, off, cursorq, x, dinv, xs2, N);
    fill_ranged<<<gR, 256, 0, stream>>>(src, dst, cursorq, csr, E, N, echunk, q1);

    // --- Layer 1: agg pre-scaled [N,2], gemm 2->128 (+b1, relu, *dinv) ---
    agg2_kernel<<<gN, 256, 0, stream>>>(xs2, off, csr, dinv, t2, N);
    gemm_small<2, 128, true, true><<<cdiv(N, 8), 256, 0, stream>>>(t2, W1, b1, dinv, bufA, N);
    // --- Layer 2: gemm 128->128 (raw, cm32 out), agg128xp2 (+b2, relu, *dinv) ---
    gemm_tiled<128, 128, false, false, 0, 32><<<gT, 256, 0, stream>>>(bufA, W2, nullptr, nullptr, bufB, N);
    agg128xp2_kernel<true, true, NG><<<gP, 256, 0, stream>>>(bufB, off, cursorq, csr, dinv, b2, bufA, bar, N);
    // --- Layer 3: gemm 128->32 (cm32 in), agg32 (+b3, relu, *dinv) ---
    gemm_tiled<128, 32, false, false, 32, 0><<<gT, 256, 0, stream>>>(bufA, W3, nullptr, nullptr, bufB, N);
    agg32_kernel<true, true><<<cdiv(N, 32), 256, 0, stream>>>(bufB, off, csr, dinv, b3, bufA, N);
    // --- Layer 4: gemm 32->32, agg32 (+b4, relu, *dinv) ---
    gemm_tiled<32, 32, false, false, 0, 0><<<gT, 256, 0, stream>>>(bufA, W4, nullptr, nullptr, bufB, N);
    agg32_kernel<true, true><<<cdiv(N, 32), 256, 0, stream>>>(bufB, off, csr, dinv, b4, bufA, N);
    // --- Layer 5: agg32 raw -> A_hat x4, fused gemm 32->64 + final 64->1 ---
    agg32_kernel<false, false><<<cdiv(N, 32), 256, 0, stream>>>(bufA, off, csr, dinv, nullptr, bufB, N);
    gemm_final<<<gT, 256, 0, stream>>>(bufB, W5, b5, Wl, bl, (float*)d_out, N);
}

// Round 6
// 655.488 us; speedup vs baseline: 1.2220x; 1.2220x over previous
//
#include <hip/hip_runtime.h>
#include <math.h>

// ---------------------------------------------------------------------------
// GCN 5-layer forward, dinv-prescaled formulation.
//   agg[v] = dinv[v] * ( sum_{s in N(v)} hs[s] + hs[v] ),  hs = dinv (.) h.
// Layer plan (narrow-side aggregation):
//   L1: agg2(xs=dinv*x) -> gemm 2->128 +b1 relu *dinv
//   L2: gemm 128->128 (cm32 out) ; agg128xp3 +b2 relu *dinv (cm32)
//   L3: gemm 128->32 (cm32 in) ; agg32 +b3 relu *dinv
//   L4: gemm 32->32   ; agg32  +b4 relu *dinv
//   L5: agg32 raw     ; gemm_final: (t5@W5+b5).relu @ Wl + bl -> out
// R19: per-XCD phase barrier. R18 CONFIRMED the locality theory (FETCH
//   327->165MB = computed compulsory floor) but the GLOBAL soft barrier
//   collapsed (365us @ 625GB/s): 968 blocks polling ONE line at s_sleep(2)
//   = poll-flood contention + thin co-residency margin (occupancy 44% vs
//   3.78 blocks/CU needed -> possible deadlock-to-cap each phase).
//   Fix: (a) barrier per (phase,class) - 92 blocks/counter, line stays in
//   its own XCD L2, s_sleep(16) poll, cap 200; (b) NG=17/launch_bounds(256,3)
//   -> grid 736 <= worst-case capacity 768 even at 170 VGPR. Predicted:
//   FETCH ~165-185MB, WRITE 50MB (spill check), dur ~60-75us.
// R18 post-mortem: locality works, sync was the cost. R17: spills (VGPR cap
//   85 < need) poisoned the first persistent attempt. R16 (NULL): data order
//   without schedule does nothing. R15 (REVERTED): 8-col chunks on latency-
//   bound agg32: 4x instructions for fewer bytes = loss. R14: XCD-sliced
//   cm32 agg128 127->98us, FETCH 414->328 (12.8MB slice > 4MB L2, hit 63%).
// Structural walls (measured): fill/count atomic floors; fp32 vector-ALU
//   gemms (no fp32 MFMA; bf16 blows the 7.9e-5 absmax budget).
// ---------------------------------------------------------------------------

static inline int cdiv(int a, int b) { return (a + b - 1) / b; }

__global__ void zero_i32(int* __restrict__ p, int n) {
    int i = blockIdx.x * 256 + threadIdx.x;
    if (i < n) p[i] = 0;
}

// Degree count per (dst, src-quartile): atomics into cntq[4N].
__global__ void count_q(const int* __restrict__ src, const int* __restrict__ dst,
                        int* __restrict__ cntq, int E, int q1) {
    int e = blockIdx.x * 256 + threadIdx.x;
    if (e < E) {
        int s = src[e];
        int q = (s >= q1) + (s >= 2 * q1) + (s >= 3 * q1);
        atomicAdd(&cntq[dst[e] * 4 + q], 1);
    }
}

// Inclusive scan per 256-block of per-node TOTALS (sum of 4 quartile counts);
// inclusive partials to off, block totals to bsum.
__global__ void scan1q(const int* __restrict__ cntq, int* __restrict__ off,
                       int* __restrict__ bsum, int n) {
    __shared__ int sm[256];
    int i = blockIdx.x * 256 + threadIdx.x;
    int v = 0;
    if (i < n) {
        int4 c = *reinterpret_cast<const int4*>(cntq + 4 * (size_t)i);
        v = c.x + c.y + c.z + c.w;
    }
    sm[threadIdx.x] = v;
    __syncthreads();
    for (int ofs = 1; ofs < 256; ofs <<= 1) {
        int t = (threadIdx.x >= (unsigned)ofs) ? sm[threadIdx.x - ofs] : 0;
        __syncthreads();
        sm[threadIdx.x] += t;
        __syncthreads();
    }
    if (i < n) off[i] = sm[threadIdx.x];
    if (threadIdx.x == 255) bsum[blockIdx.x] = sm[255];
}

// Exclusive scan of block sums (nb <= 512).
__global__ void scan2(const int* __restrict__ bsum, int* __restrict__ bpre,
                      int nb, int* __restrict__ off, int N, int E) {
    __shared__ int sm[512];
    int t = threadIdx.x;
    sm[t] = (t < nb) ? bsum[t] : 0;
    __syncthreads();
    for (int ofs = 1; ofs < 512; ofs <<= 1) {
        int v = (t >= ofs) ? sm[t - ofs] : 0;
        __syncthreads();
        sm[t] += v;
        __syncthreads();
    }
    if (t < nb) bpre[t] = sm[t] - bsum[t];
    if (t == 0) off[N] = E;
}

// Fused: finalize off (exclusive), seed 4 quartile cursors per node (seg
// starts; post-fill they hold seg ENDS), dinv=1/sqrt(deg+1), xs = dinv * x.
__global__ void scan3_fused(const int* __restrict__ cntq, const int* __restrict__ bpre,
                            int* __restrict__ off, int* __restrict__ cursorq,
                            const float* __restrict__ x, float* __restrict__ dinv,
                            float* __restrict__ xs, int n) {
    int i = blockIdx.x * 256 + threadIdx.x;
    if (i < n) {
        int4 cq = *reinterpret_cast<const int4*>(cntq + 4 * (size_t)i);
        int c = cq.x + cq.y + cq.z + cq.w;
        int o = off[i] - c + bpre[blockIdx.x];
        off[i] = o;
        int4 cur;
        cur.x = o;
        cur.y = o + cq.x;
        cur.z = o + cq.x + cq.y;
        cur.w = o + cq.x + cq.y + cq.z;
        *reinterpret_cast<int4*>(cursorq + 4 * (size_t)i) = cur;
        float dv = 1.0f / sqrtf((float)c + 1.0f);
        dinv[i] = dv;
        float2 xv = *reinterpret_cast<const float2*>(x + 2 * (size_t)i);
        *reinterpret_cast<float2*>(xs + 2 * (size_t)i) = float2{dv * xv.x, dv * xv.y};
    }
}

// XCD-class-filtered CSR fill with src-quartile bucketing: class c handles
// only its dst-range (cursorq slice ~200KB, csr slice ~800KB stay in one
// XCD's L2). Each node's edge list lands as [q0|q1|q2|q3] segments.
__global__ __launch_bounds__(256) void fill_ranged(const int* __restrict__ src,
                                                   const int* __restrict__ dst,
                                                   int* __restrict__ cursorq,
                                                   int* __restrict__ csr,
                                                   int E, int N, int echunk, int q1) {
    int cls = blockIdx.x & 7;
    int chunk = blockIdx.x >> 3;
    int per = (N + 7) >> 3;
    int lo = cls * per;
    int hi = lo + per; if (hi > N) hi = N;
    int e0 = chunk * echunk;
    int e1 = e0 + echunk; if (e1 > E) e1 = E;
    for (int e = e0 + (int)threadIdx.x; e < e1; e += 256) {
        int d = dst[e];
        if (d >= lo && d < hi) {
            int s = src[e];
            int q = (s >= q1) + (s >= 2 * q1) + (s >= 3 * q1);
            int p = atomicAdd(&cursorq[d * 4 + q], 1);
            csr[p] = s;
        }
    }
}

// ---------------------------------------------------------------------------
// Aggregation of pre-scaled [N,2] input: one thread per node.
// ---------------------------------------------------------------------------
__global__ __launch_bounds__(256) void agg2_kernel(const float* __restrict__ xs,
                                                   const int* __restrict__ off,
                                                   const int* __restrict__ csr,
                                                   const float* __restrict__ dinv,
                                                   float* __restrict__ out, int n) {
    int v = blockIdx.x * 256 + threadIdx.x;
    if (v >= n) return;
    float a0 = 0.f, a1 = 0.f;
    int e0 = off[v], e1 = off[v + 1];
    for (int e = e0; e < e1; e++) {
        int s = csr[e];
        float2 q = *reinterpret_cast<const float2*>(xs + 2 * (size_t)s);
        a0 += q.x;
        a1 += q.y;
    }
    float dv = dinv[v];
    float2 xv = *reinterpret_cast<const float2*>(xs + 2 * (size_t)v);
    *reinterpret_cast<float2*>(out + 2 * (size_t)v) =
        float2{dv * (a0 + xv.x), dv * (a1 + xv.y)};
}

// ---------------------------------------------------------------------------
// agg128xp3: F=128 aggregation, XCD-sliced AND quartile-phase-aligned with
// PER-CLASS (per-XCD) soft barriers.
// h chunk-major hc[4][N][32]; class = blockIdx&7 = (chunk, dst-half).
// Persistent co-resident grid (736 blocks <= 768 worst-case capacity at
// 170 VGPR under launch_bounds(256,3)); each block owns NG*32 = 544 nodes
// (acc[NG] in VGPRs, fully unrolled), sweeps 4 src-quartile phases
// OUTERMOST. Phase barrier is per (phase,class): 92 blocks/counter, line
// stays in its own XCD's L2; s_sleep(16) poll, cap 200 (performance-only,
// deadlock-free; timeout cannot affect correctness).
// Seg bounds: start = (q==0 ? off[v] : cur4[v*4+q-1]), end = cur4[v*4+q].
// ---------------------------------------------------------------------------
template <bool BR, bool PS, int NG>
__global__ __launch_bounds__(256, 3) void agg128xp3_kernel(const float* __restrict__ hc,
                                                           const int* __restrict__ off,
                                                           const int* __restrict__ cur4,
                                                           const int* __restrict__ csr,
                                                           const float* __restrict__ dinv,
                                                           const float* __restrict__ bias,
                                                           float* __restrict__ outc,
                                                           int* __restrict__ bar, int n) {
    int cls = blockIdx.x & 7;
    int chunk = cls >> 1;
    int half = cls & 1;
    int n2 = (n + 1) >> 1;
    int lo = half * n2;
    int hi = lo + n2; if (hi > n) hi = n;

    const float* __restrict__ h = hc + (size_t)chunk * n * 32;
    float* __restrict__ out = outc + (size_t)chunk * n * 32;

    int tid = threadIdx.x;
    int lane = tid & 63;
    int sl = lane & 7;
    int subbase = lane & ~7;
    int grpid = tid >> 3;                 // 0..31
    int nstart = lo + (blockIdx.x >> 3) * (NG * 32);
    int target = (int)(gridDim.x >> 3);   // blocks per class

    float4 acc[NG];
#pragma unroll
    for (int g = 0; g < NG; g++) acc[g] = float4{0.f, 0.f, 0.f, 0.f};

#pragma unroll 1
    for (int q = 0; q < 4; q++) {
        if (q > 0) {
            // Per-class capped soft phase barrier (performance-only).
            // Counter cacheline is private to this XCD's 92 blocks.
            if (tid == 0) {
                int* ctr = bar + ((q << 3) | cls) * 32;  // 128B-spaced counters
                atomicAdd(ctr, 1);
                volatile int* vb = ctr;
                int it = 0;
                while (*vb < target && it < 200) {
                    __builtin_amdgcn_s_sleep(16);
                    ++it;
                }
            }
            __syncthreads();
        }
#pragma unroll
        for (int g = 0; g < NG; g++) {
            int v = nstart + g * 32 + grpid;
            if (v >= hi) continue;
            int s0 = (q == 0) ? off[v] : cur4[v * 4 + q - 1];
            int s1 = cur4[v * 4 + q];
            for (int base = s0; base < s1; base += 8) {
                int m = s1 - base; if (m > 8) m = 8;
                int idx = (sl < m) ? csr[base + sl] : 0;
                // first half: lanes subbase+0..3
                int mA = (m < 4) ? m : 4;
                if (mA == 4) {
                    float4 hb[4];
#pragma unroll
                    for (int u = 0; u < 4; u++) {
                        int s = __shfl(idx, subbase + u);
                        hb[u] = *reinterpret_cast<const float4*>(h + (size_t)s * 32 + sl * 4);
                    }
#pragma unroll
                    for (int u = 0; u < 4; u++) {
                        acc[g].x += hb[u].x; acc[g].y += hb[u].y;
                        acc[g].z += hb[u].z; acc[g].w += hb[u].w;
                    }
                } else {
                    int i = 0;
                    if (i + 2 <= mA) {
                        int sa = __shfl(idx, subbase + i);
                        int sb = __shfl(idx, subbase + i + 1);
                        float4 h0 = *reinterpret_cast<const float4*>(h + (size_t)sa * 32 + sl * 4);
                        float4 h1 = *reinterpret_cast<const float4*>(h + (size_t)sb * 32 + sl * 4);
                        acc[g].x += h0.x + h1.x; acc[g].y += h0.y + h1.y;
                        acc[g].z += h0.z + h1.z; acc[g].w += h0.w + h1.w;
                        i += 2;
                    }
                    if (i < mA) {
                        int sa = __shfl(idx, subbase + i);
                        float4 h0 = *reinterpret_cast<const float4*>(h + (size_t)sa * 32 + sl * 4);
                        acc[g].x += h0.x; acc[g].y += h0.y;
                        acc[g].z += h0.z; acc[g].w += h0.w;
                    }
                }
                // second half: lanes subbase+4..7
                if (m > 4) {
                    int mB = m - 4;
                    if (mB == 4) {
                        float4 hb[4];
#pragma unroll
                        for (int u = 0; u < 4; u++) {
                            int s = __shfl(idx, subbase + 4 + u);
                            hb[u] = *reinterpret_cast<const float4*>(h + (size_t)s * 32 + sl * 4);
                        }
#pragma unroll
                        for (int u = 0; u < 4; u++) {
                            acc[g].x += hb[u].x; acc[g].y += hb[u].y;
                            acc[g].z += hb[u].z; acc[g].w += hb[u].w;
                        }
                    } else {
                        int j = 0;
                        if (j + 2 <= mB) {
                            int sa = __shfl(idx, subbase + 4 + j);
                            int sb = __shfl(idx, subbase + 4 + j + 1);
                            float4 h0 = *reinterpret_cast<const float4*>(h + (size_t)sa * 32 + sl * 4);
                            float4 h1 = *reinterpret_cast<const float4*>(h + (size_t)sb * 32 + sl * 4);
                            acc[g].x += h0.x + h1.x; acc[g].y += h0.y + h1.y;
                            acc[g].z += h0.z + h1.z; acc[g].w += h0.w + h1.w;
                            j += 2;
                        }
                        if (j < mB) {
                            int sa = __shfl(idx, subbase + 4 + j);
                            float4 h0 = *reinterpret_cast<const float4*>(h + (size_t)sa * 32 + sl * 4);
                            acc[g].x += h0.x; acc[g].y += h0.y;
                            acc[g].z += h0.z; acc[g].w += h0.w;
                        }
                    }
                }
            }
        }
    }

    // Epilogue: self-loop + bias/relu + post-scale, per owned node.
#pragma unroll
    for (int g = 0; g < NG; g++) {
        int v = nstart + g * 32 + grpid;
        if (v >= hi) continue;
        float dv = dinv[v];
        float4 hv = *reinterpret_cast<const float4*>(h + (size_t)v * 32 + sl * 4);
        float o0 = dv * (acc[g].x + hv.x);
        float o1 = dv * (acc[g].y + hv.y);
        float o2 = dv * (acc[g].z + hv.z);
        float o3 = dv * (acc[g].w + hv.w);
        if constexpr (BR) {
            float4 b = *reinterpret_cast<const float4*>(bias + chunk * 32 + sl * 4);
            o0 = fmaxf(o0 + b.x, 0.f);
            o1 = fmaxf(o1 + b.y, 0.f);
            o2 = fmaxf(o2 + b.z, 0.f);
            o3 = fmaxf(o3 + b.w, 0.f);
        }
        if constexpr (PS) {
            o0 *= dv; o1 *= dv; o2 *= dv; o3 *= dv;
        }
        *reinterpret_cast<float4*>(out + (size_t)v * 32 + sl * 4) = float4{o0, o1, o2, o3};
    }
}

// ---------------------------------------------------------------------------
// agg32: F=32, 8 lanes/node, lane owns 4 cols (float4). Dual 8-edge chunks.
// (Quartile edge order is transparent here: list walked in csr order.)
// ---------------------------------------------------------------------------
template <bool BR, bool PS>
__global__ __launch_bounds__(256) void agg32_kernel(const float* __restrict__ h,
                                                    const int* __restrict__ off,
                                                    const int* __restrict__ csr,
                                                    const float* __restrict__ dinv,
                                                    const float* __restrict__ bias,
                                                    float* __restrict__ out, int n) {
    int tid = threadIdx.x;
    int lane = tid & 63;
    int sl = lane & 7;
    int subbase = lane & ~7;
    int wave = tid >> 6;
    int v = blockIdx.x * 32 + wave * 8 + (lane >> 3);
    if (v >= n) return;

    int start = off[v];
    int end = off[v + 1];

    float4 acc = {0.f, 0.f, 0.f, 0.f};

    for (int base = start; base < end; base += 16) {
        int m = end - base;
        if (m > 16) m = 16;
        int idxA = (sl < m) ? csr[base + sl] : 0;
        int idxB = (8 + sl < m) ? csr[base + 8 + sl] : 0;
        if (m == 16) {
            float4 hb[16];
#pragma unroll
            for (int u = 0; u < 16; u++) {
                int s = __shfl((u < 8) ? idxA : idxB, subbase + (u & 7));
                hb[u] = *reinterpret_cast<const float4*>(h + (size_t)s * 32 + sl * 4);
            }
#pragma unroll
            for (int u = 0; u < 16; u++) {
                acc.x += hb[u].x; acc.y += hb[u].y; acc.z += hb[u].z; acc.w += hb[u].w;
            }
        } else {
            int ma = (m < 8) ? m : 8;
            int i = 0;
            for (; i + 4 <= ma; i += 4) {
                float4 hb[4];
#pragma unroll
                for (int u = 0; u < 4; u++) {
                    int s = __shfl(idxA, subbase + i + u);
                    hb[u] = *reinterpret_cast<const float4*>(h + (size_t)s * 32 + sl * 4);
                }
#pragma unroll
                for (int u = 0; u < 4; u++) {
                    acc.x += hb[u].x; acc.y += hb[u].y; acc.z += hb[u].z; acc.w += hb[u].w;
                }
            }
            if (i + 2 <= ma) {
                int s0 = __shfl(idxA, subbase + i);
                int s1 = __shfl(idxA, subbase + i + 1);
                float4 h0 = *reinterpret_cast<const float4*>(h + (size_t)s0 * 32 + sl * 4);
                float4 h1 = *reinterpret_cast<const float4*>(h + (size_t)s1 * 32 + sl * 4);
                acc.x += h0.x + h1.x; acc.y += h0.y + h1.y;
                acc.z += h0.z + h1.z; acc.w += h0.w + h1.w;
                i += 2;
            }
            if (i < ma) {
                int s0 = __shfl(idxA, subbase + i);
                float4 h0 = *reinterpret_cast<const float4*>(h + (size_t)s0 * 32 + sl * 4);
                acc.x += h0.x; acc.y += h0.y; acc.z += h0.z; acc.w += h0.w;
            }
            if (m > 8) {
                int mb = m - 8;
                int j = 0;
                for (; j + 4 <= mb; j += 4) {
                    float4 hb[4];
#pragma unroll
                    for (int u = 0; u < 4; u++) {
                        int s = __shfl(idxB, subbase + j + u);
                        hb[u] = *reinterpret_cast<const float4*>(h + (size_t)s * 32 + sl * 4);
                    }
#pragma unroll
                    for (int u = 0; u < 4; u++) {
                        acc.x += hb[u].x; acc.y += hb[u].y; acc.z += hb[u].z; acc.w += hb[u].w;
                    }
                }
                if (j + 2 <= mb) {
                    int s0 = __shfl(idxB, subbase + j);
                    int s1 = __shfl(idxB, subbase + j + 1);
                    float4 h0 = *reinterpret_cast<const float4*>(h + (size_t)s0 * 32 + sl * 4);
                    float4 h1 = *reinterpret_cast<const float4*>(h + (size_t)s1 * 32 + sl * 4);
                    acc.x += h0.x + h1.x; acc.y += h0.y + h1.y;
                    acc.z += h0.z + h1.z; acc.w += h0.w + h1.w;
                    j += 2;
                }
                if (j < mb) {
                    int s0 = __shfl(idxB, subbase + j);
                    float4 h0 = *reinterpret_cast<const float4*>(h + (size_t)s0 * 32 + sl * 4);
                    acc.x += h0.x; acc.y += h0.y; acc.z += h0.z; acc.w += h0.w;
                }
            }
        }
    }

    float dv = dinv[v];
    float4 hv = *reinterpret_cast<const float4*>(h + (size_t)v * 32 + sl * 4);
    float o0 = dv * (acc.x + hv.x);
    float o1 = dv * (acc.y + hv.y);
    float o2 = dv * (acc.z + hv.z);
    float o3 = dv * (acc.w + hv.w);
    if constexpr (BR) {
        float4 b = *reinterpret_cast<const float4*>(bias + sl * 4);
        o0 = fmaxf(o0 + b.x, 0.f);
        o1 = fmaxf(o1 + b.y, 0.f);
        o2 = fmaxf(o2 + b.z, 0.f);
        o3 = fmaxf(o3 + b.w, 0.f);
    }
    if constexpr (PS) {
        o0 *= dv; o1 *= dv; o2 *= dv; o3 *= dv;
    }
    *reinterpret_cast<float4*>(out + (size_t)v * 32 + sl * 4) = float4{o0, o1, o2, o3};
}

// ---------------------------------------------------------------------------
// Register-tiled GEMM: h[N,F] = x[N,K] @ W[K,F]; epilogue +bias/relu (BR),
// *dinv[row] (PS). KC=32 (KCP=36 breaks pow-2 banks): K=128 -> 4 chunks,
// K=32 -> single chunk (2 barriers).
// CIN/COUT: 0 = row-major, 32 = chunk-major [F/32][N][32] (for agg128xp3).
// ---------------------------------------------------------------------------
template <int K, int F, bool BR, bool PS, int CIN = 0, int COUT = 0>
__global__ __launch_bounds__(256, 4) void gemm_tiled(const float* __restrict__ x,
                                                     const float* __restrict__ W,
                                                     const float* __restrict__ bias,
                                                     const float* __restrict__ dinv,
                                                     float* __restrict__ h, int n) {
    constexpr int KC = 32;
    constexpr int KCP = 36;             // padded row stride (144 B, 16B-aligned)
    constexpr int ROWS = 64;
    constexpr int TPC = F / 4;
    constexpr int RT = 256 / TPC;
    constexpr int RPT = ROWS / RT;
    static_assert(K % KC == 0, "K must be a multiple of 32");

    __shared__ float Ws[KC * F];
    __shared__ float Xs[ROWS * KCP];

    const int tid = threadIdx.x;
    const int cb = (tid % TPC) * 4;
    const int tr = tid / TPC;
    const int row0 = blockIdx.x * ROWS;

    float acc[RPT][4];
#pragma unroll
    for (int r = 0; r < RPT; r++)
#pragma unroll
        for (int j = 0; j < 4; j++) acc[r][j] = 0.f;

#pragma unroll 1
    for (int k0 = 0; k0 < K; k0 += KC) {
        __syncthreads();
        {
            // Stage x chunk: 64 rows x 32 cols; thread -> row tid>>2, 8 cols.
            int r = tid >> 2;
            int kk = (tid & 3) * 8;
            int gr = row0 + r;
            float4 v0 = {0.f, 0.f, 0.f, 0.f}, v1 = {0.f, 0.f, 0.f, 0.f};
            if (gr < n) {
                if constexpr (CIN == 32) {
                    const float* xb = x + (size_t)(k0 >> 5) * n * 32 + (size_t)gr * 32 + kk;
                    v0 = *reinterpret_cast<const float4*>(xb);
                    v1 = *reinterpret_cast<const float4*>(xb + 4);
                } else {
                    v0 = *reinterpret_cast<const float4*>(x + (size_t)gr * K + k0 + kk);
                    v1 = *reinterpret_cast<const float4*>(x + (size_t)gr * K + k0 + kk + 4);
                }
            }
            *reinterpret_cast<float4*>(&Xs[r * KCP + kk]) = v0;
            *reinterpret_cast<float4*>(&Xs[r * KCP + kk + 4]) = v1;
        }
        for (int i = tid; i < KC * F / 4; i += 256) {
            *reinterpret_cast<float4*>(&Ws[i * 4]) =
                *reinterpret_cast<const float4*>(W + (size_t)k0 * F + i * 4);
        }
        __syncthreads();

#pragma unroll 4
        for (int kk4 = 0; kk4 < KC; kk4 += 4) {
            float4 xr[RPT];
#pragma unroll
            for (int r = 0; r < RPT; r++)
                xr[r] = *reinterpret_cast<const float4*>(&Xs[(tr * RPT + r) * KCP + kk4]);
#pragma unroll
            for (int j = 0; j < 4; j++) {
                float4 w = *reinterpret_cast<const float4*>(&Ws[(kk4 + j) * F + cb]);
#pragma unroll
                for (int r = 0; r < RPT; r++) {
                    float xv = (j == 0) ? xr[r].x : (j == 1) ? xr[r].y
                             : (j == 2) ? xr[r].z : xr[r].w;
                    acc[r][0] += xv * w.x;
                    acc[r][1] += xv * w.y;
                    acc[r][2] += xv * w.z;
                    acc[r][3] += xv * w.w;
                }
            }
        }
    }

    float4 b = float4{0.f, 0.f, 0.f, 0.f};
    if constexpr (BR) b = *reinterpret_cast<const float4*>(bias + cb);
#pragma unroll
    for (int r = 0; r < RPT; r++) {
        int row = row0 + tr * RPT + r;
        if (row < n) {
            float o0 = acc[r][0], o1 = acc[r][1], o2 = acc[r][2], o3 = acc[r][3];
            if constexpr (BR) {
                o0 = fmaxf(o0 + b.x, 0.f);
                o1 = fmaxf(o1 + b.y, 0.f);
                o2 = fmaxf(o2 + b.z, 0.f);
                o3 = fmaxf(o3 + b.w, 0.f);
            }
            if constexpr (PS) {
                float dv = dinv[row];
                o0 *= dv; o1 *= dv; o2 *= dv; o3 *= dv;
            }
            if constexpr (COUT == 32) {
                float* hb = h + (size_t)(cb >> 5) * n * 32 + (size_t)row * 32 + (cb & 31);
                *reinterpret_cast<float4*>(hb) = float4{o0, o1, o2, o3};
            } else {
                *reinterpret_cast<float4*>(&h[(size_t)row * F + cb]) = float4{o0, o1, o2, o3};
            }
        }
    }
}

// ---------------------------------------------------------------------------
// Fused L5 + final: out[v] = relu(t5[v]@W5 + b5) . Wl + bl.  K=32, F=64.
// Single KC=32 chunk; row outputs in 16 lanes x 4 regs -> dot with Wl (LDS)
// then 4-step shfl-xor reduce; lane0-of-16 writes out[row].
// ---------------------------------------------------------------------------
__global__ __launch_bounds__(256, 4) void gemm_final(const float* __restrict__ x,
                                                     const float* __restrict__ W,
                                                     const float* __restrict__ bias,
                                                     const float* __restrict__ Wl,
                                                     const float* __restrict__ bl,
                                                     float* __restrict__ out, int n) {
    constexpr int K = 32, F = 64;
    constexpr int KC = 32;
    constexpr int KCP = 36;
    constexpr int ROWS = 64;
    constexpr int TPC = F / 4;          // 16
    constexpr int RT = 256 / TPC;       // 16
    constexpr int RPT = ROWS / RT;      // 4

    __shared__ float Ws[KC * F];
    __shared__ float Xs[ROWS * KCP];
    __shared__ float wl[F];

    const int tid = threadIdx.x;
    if (tid < F) wl[tid] = Wl[tid];
    const int cb = (tid % TPC) * 4;
    const int tr = tid / TPC;
    const int row0 = blockIdx.x * ROWS;

    float acc[RPT][4];
#pragma unroll
    for (int r = 0; r < RPT; r++)
#pragma unroll
        for (int j = 0; j < 4; j++) acc[r][j] = 0.f;

    {
        {
            int r = tid >> 2;
            int kk = (tid & 3) * 8;
            int gr = row0 + r;
            float4 v0 = {0.f, 0.f, 0.f, 0.f}, v1 = {0.f, 0.f, 0.f, 0.f};
            if (gr < n) {
                v0 = *reinterpret_cast<const float4*>(x + (size_t)gr * K + kk);
                v1 = *reinterpret_cast<const float4*>(x + (size_t)gr * K + kk + 4);
            }
            *reinterpret_cast<float4*>(&Xs[r * KCP + kk]) = v0;
            *reinterpret_cast<float4*>(&Xs[r * KCP + kk + 4]) = v1;
        }
        for (int i = tid; i < KC * F / 4; i += 256) {
            *reinterpret_cast<float4*>(&Ws[i * 4]) =
                *reinterpret_cast<const float4*>(W + i * 4);
        }
        __syncthreads();

#pragma unroll 4
        for (int kk4 = 0; kk4 < KC; kk4 += 4) {
            float4 xr[RPT];
#pragma unroll
            for (int r = 0; r < RPT; r++)
                xr[r] = *reinterpret_cast<const float4*>(&Xs[(tr * RPT + r) * KCP + kk4]);
#pragma unroll
            for (int j = 0; j < 4; j++) {
                float4 w = *reinterpret_cast<const float4*>(&Ws[(kk4 + j) * F + cb]);
#pragma unroll
                for (int r = 0; r < RPT; r++) {
                    float xv = (j == 0) ? xr[r].x : (j == 1) ? xr[r].y
                             : (j == 2) ? xr[r].z : xr[r].w;
                    acc[r][0] += xv * w.x;
                    acc[r][1] += xv * w.y;
                    acc[r][2] += xv * w.z;
                    acc[r][3] += xv * w.w;
                }
            }
        }
    }

    float4 b = *reinterpret_cast<const float4*>(bias + cb);
    float4 w = *reinterpret_cast<const float4*>(&wl[cb]);
    float blv = bl[0];
#pragma unroll
    for (int r = 0; r < RPT; r++) {
        int row = row0 + tr * RPT + r;
        float o0 = fmaxf(acc[r][0] + b.x, 0.f);
        float o1 = fmaxf(acc[r][1] + b.y, 0.f);
        float o2 = fmaxf(acc[r][2] + b.z, 0.f);
        float o3 = fmaxf(acc[r][3] + b.w, 0.f);
        float partial = o0 * w.x + o1 * w.y + o2 * w.z + o3 * w.w;
        partial += __shfl_xor(partial, 8, 16);
        partial += __shfl_xor(partial, 4, 16);
        partial += __shfl_xor(partial, 2, 16);
        partial += __shfl_xor(partial, 1, 16);
        if ((tid & 15) == 0 && row < n) out[row] = partial + blv;
    }
}

// Simple GEMM for K=2 (layer 1), epilogue +bias/relu (BR), *dinv (PS).
template <int K, int F, bool BR, bool PS>
__global__ __launch_bounds__(256, 4) void gemm_small(const float* __restrict__ x,
                                                     const float* __restrict__ W,
                                                     const float* __restrict__ bias,
                                                     const float* __restrict__ dinv,
                                                     float* __restrict__ h, int n) {
    constexpr int TPR = F / 4;
    constexpr int ROWS = 256 / TPR;
    __shared__ float Ws[K * F];
    for (int i = threadIdx.x; i < K * F; i += 256) Ws[i] = W[i];
    __syncthreads();

    int tid = threadIdx.x;
    int cb = (tid % TPR) * 4;
    int r = blockIdx.x * ROWS + tid / TPR;
    if (r >= n) return;

    const float* xr = x + (size_t)r * K;
    float a0 = 0.f, a1 = 0.f, a2 = 0.f, a3 = 0.f;
#pragma unroll
    for (int k = 0; k < K; k++) {
        float xv = xr[k];
        float4 w = *reinterpret_cast<const float4*>(&Ws[k * F + cb]);
        a0 += xv * w.x; a1 += xv * w.y; a2 += xv * w.z; a3 += xv * w.w;
    }
    if constexpr (BR) {
        float4 b = *reinterpret_cast<const float4*>(bias + cb);
        a0 = fmaxf(a0 + b.x, 0.f);
        a1 = fmaxf(a1 + b.y, 0.f);
        a2 = fmaxf(a2 + b.z, 0.f);
        a3 = fmaxf(a3 + b.w, 0.f);
    }
    if constexpr (PS) {
        float dv = dinv[r];
        a0 *= dv; a1 *= dv; a2 *= dv; a3 *= dv;
    }
    *reinterpret_cast<float4*>(&h[(size_t)r * F + cb]) = float4{a0, a1, a2, a3};
}

extern "C" void kernel_launch(void* const* d_in, const int* in_sizes, int n_in,
                              void* d_out, int out_size, void* d_ws, size_t ws_size,
                              hipStream_t stream) {
    const float* x = (const float*)d_in[0];
    const int* ei = (const int*)d_in[1];
    const float* W1 = (const float*)d_in[3];
    const float* b1 = (const float*)d_in[4];
    const float* W2 = (const float*)d_in[5];
    const float* b2 = (const float*)d_in[6];
    const float* W3 = (const float*)d_in[7];
    const float* b3 = (const float*)d_in[8];
    const float* W4 = (const float*)d_in[9];
    const float* b4 = (const float*)d_in[10];
    const float* W5 = (const float*)d_in[11];
    const float* b5 = (const float*)d_in[12];
    const float* Wl = (const float*)d_in[13];
    const float* bl = (const float*)d_in[14];

    const int N = in_sizes[0] / 2;
    const int E = in_sizes[1] / 2;
    const int* src = ei;
    const int* dst = ei + E;

    char* wp = (char*)d_ws;
    auto alloc = [&](size_t bytes) -> void* {
        void* p = wp;
        wp += ((bytes + 255) / 256) * 256;
        return p;
    };
    int* cntq = (int*)alloc((size_t)N * 4 * 4);
    int* off = (int*)alloc((size_t)(N + 1) * 4);
    int* cursorq = (int*)alloc((size_t)N * 4 * 4);
    int* bsum = (int*)alloc(512 * 4);
    int* bpre = (int*)alloc(512 * 4);
    int* bar = (int*)alloc(4 * 8 * 32 * 4);   // (phase,class) counters, 128B apart
    int* csr = (int*)alloc((size_t)E * 4);
    float* dinv = (float*)alloc((size_t)N * 4);
    float* xs2 = (float*)alloc((size_t)N * 2 * 4);
    float* t2 = (float*)alloc((size_t)N * 2 * 4);
    float* bufA = (float*)alloc((size_t)N * 128 * 4);
    float* bufB = (float*)alloc((size_t)N * 128 * 4);

    const int gN = cdiv(N, 256);
    const int gE = cdiv(E, 256);
    const int nb = gN;
    const int gT = cdiv(N, 64);
    const int q1 = (N + 3) / 4;         // src quartile width

    // Ranged fill grid: 8 classes x 128 chunks.
    const int NCHUNK = 128;
    const int echunk = cdiv(E, NCHUNK);
    const int gR = 8 * NCHUNK;

    // agg128xp3 persistent grid: 8 classes x BPC blocks. NG=17 -> 544
    // nodes/block; BPC=92; grid 736 <= worst-case co-resident capacity 768
    // (3 blocks/CU at the launch_bounds(256,3) VGPR ceiling of 170).
    constexpr int NG = 17;
    const int BPC = cdiv((N + 1) / 2, NG * 32);
    const int gP = 8 * BPC;

    // --- CSR build (src-quartile-bucketed edge order) ---
    zero_i32<<<cdiv(4 * N, 256), 256, 0, stream>>>(cntq, 4 * N);
    zero_i32<<<4, 256, 0, stream>>>(bar, 4 * 8 * 32);
    count_q<<<gE, 256, 0, stream>>>(src, dst, cntq, E, q1);
    scan1q<<<nb, 256, 0, stream>>>(cntq, off, bsum, N);
    scan2<<<1, 512, 0, stream>>>(bsum, bpre, nb, off, N, E);
    scan3_fused<<<nb, 256, 0, stream>>>(cntq, bpre, off, cursorq, x, dinv, xs2, N);
    fill_ranged<<<gR, 256, 0, stream>>>(src, dst, cursorq, csr, E, N, echunk, q1);

    // --- Layer 1: agg pre-scaled [N,2], gemm 2->128 (+b1, relu, *dinv) ---
    agg2_kernel<<<gN, 256, 0, stream>>>(xs2, off, csr, dinv, t2, N);
    gemm_small<2, 128, true, true><<<cdiv(N, 8), 256, 0, stream>>>(t2, W1, b1, dinv, bufA, N);
    // --- Layer 2: gemm 128->128 (raw, cm32 out), agg128xp3 (+b2, relu, *dinv) ---
    gemm_tiled<128, 128, false, false, 0, 32><<<gT, 256, 0, stream>>>(bufA, W2, nullptr, nullptr, bufB, N);
    agg128xp3_kernel<true, true, NG><<<gP, 256, 0, stream>>>(bufB, off, cursorq, csr, dinv, b2, bufA, bar, N);
    // --- Layer 3: gemm 128->32 (cm32 in), agg32 (+b3, relu, *dinv) ---
    gemm_tiled<128, 32, false, false, 32, 0><<<gT, 256, 0, stream>>>(bufA, W3, nullptr, nullptr, bufB, N);
    agg32_kernel<true, true><<<cdiv(N, 32), 256, 0, stream>>>(bufB, off, csr, dinv, b3, bufA, N);
    // --- Layer 4: gemm 32->32, agg32 (+b4, relu, *dinv) ---
    gemm_tiled<32, 32, false, false, 0, 0><<<gT, 256, 0, stream>>>(bufA, W4, nullptr, nullptr, bufB, N);
    agg32_kernel<true, true><<<cdiv(N, 32), 256, 0, stream>>>(bufB, off, csr, dinv, b4, bufA, N);
    // --- Layer 5: agg32 raw -> A_hat x4, fused gemm 32->64 + final 64->1 ---
    agg32_kernel<false, false><<<cdiv(N, 32), 256, 0, stream>>>(bufA, off, csr, dinv, nullptr, bufB, N);
    gemm_final<<<gT, 256, 0, stream>>>(bufB, W5, b5, Wl, bl, (float*)d_out, N);
}

// Round 8
// 511.497 us; speedup vs baseline: 1.5659x; 1.2815x over previous
//
#include <hip/hip_runtime.h>
#include <math.h>

// ---------------------------------------------------------------------------
// GCN 5-layer forward, dinv-prescaled formulation.
//   agg[v] = dinv[v] * ( sum_{s in N(v)} hs[s] + hs[v] ),  hs = dinv (.) h.
// Layer plan (narrow-side aggregation; D(XW)=(DX)W commuting):
//   L1: agg2(xs=dinv*x) -> gemm 2->128 +b1 relu *dinv
//   L2: gemm 128->128 (cm32 out) ; agg128x +b2 relu *dinv (cm32)
//   L3: gemm 128->32 (cm32 in) ; agg32mm: agg +b3 relu *dinv THEN @W4 fused
//   L4: agg32 +b4 relu *dinv
//   L5: agg32fin: raw agg THEN (@W5+b5).relu@Wl+bl fused -> out
// R21: RESUBMIT of R20 — bench infra failed twice ("container failed"),
//   kernel never executed. Source audited: no spins/barriers, LDS staging
//   in-bounds, syncthreads before divergent returns, fusion math verified.
// R20: barrier family CLOSED per R19 falsifier (3 strikes: R17 spills, R18
//   global-barrier collapse, R19 per-XCD barrier deadlock-to-cap — occupancy
//   30% => ~2.4 blocks/CU co-resident < required, every phase ran to its
//   cap; FETCH 167MB proved locality, sync cost ate it). Reverted agg128 to
//   R14/R16 version (98us, FETCH 327MB). This round: fuse gemm_L4 into
//   agg32_L3's epilogue (agg32mm: 32 shfl broadcasts + W4 from 4KB LDS) and
//   gemm_final into agg32_L5's (agg32fin: W5 8KB LDS, 8-lane reduce).
//   Kills 2 dispatches + 2x ~25.6MB round-trips; epilogue VALU hidden under
//   the latency-bound gather. Predicted total 526 -> ~500.
// R16 (base, 526us): quartile CSR build (harmless to agg kernels).
// R15 (REVERTED): 8-col chunks on latency-bound agg32: 4x instructions for
//   fewer bytes = loss. R14: XCD-sliced cm32 agg128 127->98us, FETCH
//   414->328 (12.8MB slice > 4MB L2 caps hit ~63%).
// Structural walls (measured): agg128x ~98us random-gather wall; agg32
//   ~45us each (invariant across wave shapes); fill/count atomic floors;
//   fp32 vector-ALU gemms (no fp32 MFMA; plain bf16 blows 7.9e-5 absmax).
// ---------------------------------------------------------------------------

static inline int cdiv(int a, int b) { return (a + b - 1) / b; }

__global__ void zero_i32(int* __restrict__ p, int n) {
    int i = blockIdx.x * 256 + threadIdx.x;
    if (i < n) p[i] = 0;
}

// Degree count per (dst, src-quartile): atomics into cntq[4N].
__global__ void count_q(const int* __restrict__ src, const int* __restrict__ dst,
                        int* __restrict__ cntq, int E, int q1) {
    int e = blockIdx.x * 256 + threadIdx.x;
    if (e < E) {
        int s = src[e];
        int q = (s >= q1) + (s >= 2 * q1) + (s >= 3 * q1);
        atomicAdd(&cntq[dst[e] * 4 + q], 1);
    }
}

// Inclusive scan per 256-block of per-node TOTALS; block totals to bsum.
__global__ void scan1q(const int* __restrict__ cntq, int* __restrict__ off,
                       int* __restrict__ bsum, int n) {
    __shared__ int sm[256];
    int i = blockIdx.x * 256 + threadIdx.x;
    int v = 0;
    if (i < n) {
        int4 c = *reinterpret_cast<const int4*>(cntq + 4 * (size_t)i);
        v = c.x + c.y + c.z + c.w;
    }
    sm[threadIdx.x] = v;
    __syncthreads();
    for (int ofs = 1; ofs < 256; ofs <<= 1) {
        int t = (threadIdx.x >= (unsigned)ofs) ? sm[threadIdx.x - ofs] : 0;
        __syncthreads();
        sm[threadIdx.x] += t;
        __syncthreads();
    }
    if (i < n) off[i] = sm[threadIdx.x];
    if (threadIdx.x == 255) bsum[blockIdx.x] = sm[255];
}

// Exclusive scan of block sums (nb <= 512).
__global__ void scan2(const int* __restrict__ bsum, int* __restrict__ bpre,
                      int nb, int* __restrict__ off, int N, int E) {
    __shared__ int sm[512];
    int t = threadIdx.x;
    sm[t] = (t < nb) ? bsum[t] : 0;
    __syncthreads();
    for (int ofs = 1; ofs < 512; ofs <<= 1) {
        int v = (t >= ofs) ? sm[t - ofs] : 0;
        __syncthreads();
        sm[t] += v;
        __syncthreads();
    }
    if (t < nb) bpre[t] = sm[t] - bsum[t];
    if (t == 0) off[N] = E;
}

// Fused: finalize off (exclusive), seed 4 quartile cursors per node,
// dinv=1/sqrt(deg+1), xs = dinv * x.
__global__ void scan3_fused(const int* __restrict__ cntq, const int* __restrict__ bpre,
                            int* __restrict__ off, int* __restrict__ cursorq,
                            const float* __restrict__ x, float* __restrict__ dinv,
                            float* __restrict__ xs, int n) {
    int i = blockIdx.x * 256 + threadIdx.x;
    if (i < n) {
        int4 cq = *reinterpret_cast<const int4*>(cntq + 4 * (size_t)i);
        int c = cq.x + cq.y + cq.z + cq.w;
        int o = off[i] - c + bpre[blockIdx.x];
        off[i] = o;
        int4 cur;
        cur.x = o;
        cur.y = o + cq.x;
        cur.z = o + cq.x + cq.y;
        cur.w = o + cq.x + cq.y + cq.z;
        *reinterpret_cast<int4*>(cursorq + 4 * (size_t)i) = cur;
        float dv = 1.0f / sqrtf((float)c + 1.0f);
        dinv[i] = dv;
        float2 xv = *reinterpret_cast<const float2*>(x + 2 * (size_t)i);
        *reinterpret_cast<float2*>(xs + 2 * (size_t)i) = float2{dv * xv.x, dv * xv.y};
    }
}

// XCD-class-filtered CSR fill with src-quartile bucketing.
__global__ __launch_bounds__(256) void fill_ranged(const int* __restrict__ src,
                                                   const int* __restrict__ dst,
                                                   int* __restrict__ cursorq,
                                                   int* __restrict__ csr,
                                                   int E, int N, int echunk, int q1) {
    int cls = blockIdx.x & 7;
    int chunk = blockIdx.x >> 3;
    int per = (N + 7) >> 3;
    int lo = cls * per;
    int hi = lo + per; if (hi > N) hi = N;
    int e0 = chunk * echunk;
    int e1 = e0 + echunk; if (e1 > E) e1 = E;
    for (int e = e0 + (int)threadIdx.x; e < e1; e += 256) {
        int d = dst[e];
        if (d >= lo && d < hi) {
            int s = src[e];
            int q = (s >= q1) + (s >= 2 * q1) + (s >= 3 * q1);
            int p = atomicAdd(&cursorq[d * 4 + q], 1);
            csr[p] = s;
        }
    }
}

// ---------------------------------------------------------------------------
// Aggregation of pre-scaled [N,2] input: one thread per node.
// ---------------------------------------------------------------------------
__global__ __launch_bounds__(256) void agg2_kernel(const float* __restrict__ xs,
                                                   const int* __restrict__ off,
                                                   const int* __restrict__ csr,
                                                   const float* __restrict__ dinv,
                                                   float* __restrict__ out, int n) {
    int v = blockIdx.x * 256 + threadIdx.x;
    if (v >= n) return;
    float a0 = 0.f, a1 = 0.f;
    int e0 = off[v], e1 = off[v + 1];
    for (int e = e0; e < e1; e++) {
        int s = csr[e];
        float2 q = *reinterpret_cast<const float2*>(xs + 2 * (size_t)s);
        a0 += q.x;
        a1 += q.y;
    }
    float dv = dinv[v];
    float2 xv = *reinterpret_cast<const float2*>(xs + 2 * (size_t)v);
    *reinterpret_cast<float2*>(out + 2 * (size_t)v) =
        float2{dv * (a0 + xv.x), dv * (a1 + xv.y)};
}

// ---------------------------------------------------------------------------
// agg128x: F=128 aggregation, XCD-sliced. h is chunk-major hc[4][N][32].
// class = blockIdx&7: chunk = cls>>1 (32-col slice), half = cls&1 (dst half).
// ---------------------------------------------------------------------------
template <bool BR, bool PS>
__global__ __launch_bounds__(256) void agg128x_kernel(const float* __restrict__ hc,
                                                      const int* __restrict__ off,
                                                      const int* __restrict__ csr,
                                                      const float* __restrict__ dinv,
                                                      const float* __restrict__ bias,
                                                      float* __restrict__ outc, int n) {
    int cls = blockIdx.x & 7;
    int chunk = cls >> 1;
    int half = cls & 1;
    int n2 = (n + 1) >> 1;
    int lo = half * n2;
    int hi = lo + n2; if (hi > n) hi = n;

    const float* __restrict__ h = hc + (size_t)chunk * n * 32;
    float* __restrict__ out = outc + (size_t)chunk * n * 32;

    int tid = threadIdx.x;
    int lane = tid & 63;
    int sl = lane & 7;
    int subbase = lane & ~7;
    int wave = tid >> 6;
    int v = lo + (blockIdx.x >> 3) * 32 + wave * 8 + (lane >> 3);
    if (v >= hi) return;

    int start = off[v];
    int end = off[v + 1];

    float4 acc = {0.f, 0.f, 0.f, 0.f};

    for (int base = start; base < end; base += 16) {
        int m = end - base;
        if (m > 16) m = 16;
        int idxA = (sl < m) ? csr[base + sl] : 0;
        int idxB = (8 + sl < m) ? csr[base + 8 + sl] : 0;
        if (m == 16) {
            float4 hb[16];
#pragma unroll
            for (int u = 0; u < 16; u++) {
                int s = __shfl((u < 8) ? idxA : idxB, subbase + (u & 7));
                hb[u] = *reinterpret_cast<const float4*>(h + (size_t)s * 32 + sl * 4);
            }
#pragma unroll
            for (int u = 0; u < 16; u++) {
                acc.x += hb[u].x; acc.y += hb[u].y; acc.z += hb[u].z; acc.w += hb[u].w;
            }
        } else {
            int ma = (m < 8) ? m : 8;
            int i = 0;
            for (; i + 4 <= ma; i += 4) {
                float4 hb[4];
#pragma unroll
                for (int u = 0; u < 4; u++) {
                    int s = __shfl(idxA, subbase + i + u);
                    hb[u] = *reinterpret_cast<const float4*>(h + (size_t)s * 32 + sl * 4);
                }
#pragma unroll
                for (int u = 0; u < 4; u++) {
                    acc.x += hb[u].x; acc.y += hb[u].y; acc.z += hb[u].z; acc.w += hb[u].w;
                }
            }
            if (i + 2 <= ma) {
                int s0 = __shfl(idxA, subbase + i);
                int s1 = __shfl(idxA, subbase + i + 1);
                float4 h0 = *reinterpret_cast<const float4*>(h + (size_t)s0 * 32 + sl * 4);
                float4 h1 = *reinterpret_cast<const float4*>(h + (size_t)s1 * 32 + sl * 4);
                acc.x += h0.x + h1.x; acc.y += h0.y + h1.y;
                acc.z += h0.z + h1.z; acc.w += h0.w + h1.w;
                i += 2;
            }
            if (i < ma) {
                int s0 = __shfl(idxA, subbase + i);
                float4 h0 = *reinterpret_cast<const float4*>(h + (size_t)s0 * 32 + sl * 4);
                acc.x += h0.x; acc.y += h0.y; acc.z += h0.z; acc.w += h0.w;
            }
            if (m > 8) {
                int mb = m - 8;
                int j = 0;
                for (; j + 4 <= mb; j += 4) {
                    float4 hb[4];
#pragma unroll
                    for (int u = 0; u < 4; u++) {
                        int s = __shfl(idxB, subbase + j + u);
                        hb[u] = *reinterpret_cast<const float4*>(h + (size_t)s * 32 + sl * 4);
                    }
#pragma unroll
                    for (int u = 0; u < 4; u++) {
                        acc.x += hb[u].x; acc.y += hb[u].y; acc.z += hb[u].z; acc.w += hb[u].w;
                    }
                }
                if (j + 2 <= mb) {
                    int s0 = __shfl(idxB, subbase + j);
                    int s1 = __shfl(idxB, subbase + j + 1);
                    float4 h0 = *reinterpret_cast<const float4*>(h + (size_t)s0 * 32 + sl * 4);
                    float4 h1 = *reinterpret_cast<const float4*>(h + (size_t)s1 * 32 + sl * 4);
                    acc.x += h0.x + h1.x; acc.y += h0.y + h1.y;
                    acc.z += h0.z + h1.z; acc.w += h0.w + h1.w;
                    j += 2;
                }
                if (j < mb) {
                    int s0 = __shfl(idxB, subbase + j);
                    float4 h0 = *reinterpret_cast<const float4*>(h + (size_t)s0 * 32 + sl * 4);
                    acc.x += h0.x; acc.y += h0.y; acc.z += h0.z; acc.w += h0.w;
                }
            }
        }
    }

    float dv = dinv[v];
    float4 hv = *reinterpret_cast<const float4*>(h + (size_t)v * 32 + sl * 4);
    float o0 = dv * (acc.x + hv.x);
    float o1 = dv * (acc.y + hv.y);
    float o2 = dv * (acc.z + hv.z);
    float o3 = dv * (acc.w + hv.w);
    if constexpr (BR) {
        float4 b = *reinterpret_cast<const float4*>(bias + chunk * 32 + sl * 4);
        o0 = fmaxf(o0 + b.x, 0.f);
        o1 = fmaxf(o1 + b.y, 0.f);
        o2 = fmaxf(o2 + b.z, 0.f);
        o3 = fmaxf(o3 + b.w, 0.f);
    }
    if constexpr (PS) {
        o0 *= dv; o1 *= dv; o2 *= dv; o3 *= dv;
    }
    *reinterpret_cast<float4*>(out + (size_t)v * 32 + sl * 4) = float4{o0, o1, o2, o3};
}

// ---------------------------------------------------------------------------
// Shared agg32 gather body: 8 lanes/node, lane owns 4 cols. Returns acc.
// ---------------------------------------------------------------------------
__device__ __forceinline__ float4 agg32_gather(const float* __restrict__ h,
                                               const int* __restrict__ csr,
                                               int start, int end,
                                               int sl, int subbase) {
    float4 acc = {0.f, 0.f, 0.f, 0.f};
    for (int base = start; base < end; base += 16) {
        int m = end - base;
        if (m > 16) m = 16;
        int idxA = (sl < m) ? csr[base + sl] : 0;
        int idxB = (8 + sl < m) ? csr[base + 8 + sl] : 0;
        if (m == 16) {
            float4 hb[16];
#pragma unroll
            for (int u = 0; u < 16; u++) {
                int s = __shfl((u < 8) ? idxA : idxB, subbase + (u & 7));
                hb[u] = *reinterpret_cast<const float4*>(h + (size_t)s * 32 + sl * 4);
            }
#pragma unroll
            for (int u = 0; u < 16; u++) {
                acc.x += hb[u].x; acc.y += hb[u].y; acc.z += hb[u].z; acc.w += hb[u].w;
            }
        } else {
            int ma = (m < 8) ? m : 8;
            int i = 0;
            for (; i + 4 <= ma; i += 4) {
                float4 hb[4];
#pragma unroll
                for (int u = 0; u < 4; u++) {
                    int s = __shfl(idxA, subbase + i + u);
                    hb[u] = *reinterpret_cast<const float4*>(h + (size_t)s * 32 + sl * 4);
                }
#pragma unroll
                for (int u = 0; u < 4; u++) {
                    acc.x += hb[u].x; acc.y += hb[u].y; acc.z += hb[u].z; acc.w += hb[u].w;
                }
            }
            if (i + 2 <= ma) {
                int s0 = __shfl(idxA, subbase + i);
                int s1 = __shfl(idxA, subbase + i + 1);
                float4 h0 = *reinterpret_cast<const float4*>(h + (size_t)s0 * 32 + sl * 4);
                float4 h1 = *reinterpret_cast<const float4*>(h + (size_t)s1 * 32 + sl * 4);
                acc.x += h0.x + h1.x; acc.y += h0.y + h1.y;
                acc.z += h0.z + h1.z; acc.w += h0.w + h1.w;
                i += 2;
            }
            if (i < ma) {
                int s0 = __shfl(idxA, subbase + i);
                float4 h0 = *reinterpret_cast<const float4*>(h + (size_t)s0 * 32 + sl * 4);
                acc.x += h0.x; acc.y += h0.y; acc.z += h0.z; acc.w += h0.w;
            }
            if (m > 8) {
                int mb = m - 8;
                int j = 0;
                for (; j + 4 <= mb; j += 4) {
                    float4 hb[4];
#pragma unroll
                    for (int u = 0; u < 4; u++) {
                        int s = __shfl(idxB, subbase + j + u);
                        hb[u] = *reinterpret_cast<const float4*>(h + (size_t)s * 32 + sl * 4);
                    }
#pragma unroll
                    for (int u = 0; u < 4; u++) {
                        acc.x += hb[u].x; acc.y += hb[u].y; acc.z += hb[u].z; acc.w += hb[u].w;
                    }
                }
                if (j + 2 <= mb) {
                    int s0 = __shfl(idxB, subbase + j);
                    int s1 = __shfl(idxB, subbase + j + 1);
                    float4 h0 = *reinterpret_cast<const float4*>(h + (size_t)s0 * 32 + sl * 4);
                    float4 h1 = *reinterpret_cast<const float4*>(h + (size_t)s1 * 32 + sl * 4);
                    acc.x += h0.x + h1.x; acc.y += h0.y + h1.y;
                    acc.z += h0.z + h1.z; acc.w += h0.w + h1.w;
                    j += 2;
                }
                if (j < mb) {
                    int s0 = __shfl(idxB, subbase + j);
                    float4 h0 = *reinterpret_cast<const float4*>(h + (size_t)s0 * 32 + sl * 4);
                    acc.x += h0.x; acc.y += h0.y; acc.z += h0.z; acc.w += h0.w;
                }
            }
        }
    }
    return acc;
}

// ---------------------------------------------------------------------------
// agg32: plain F=32 aggregation (+bias/relu BR, post-scale PS).
// ---------------------------------------------------------------------------
template <bool BR, bool PS>
__global__ __launch_bounds__(256) void agg32_kernel(const float* __restrict__ h,
                                                    const int* __restrict__ off,
                                                    const int* __restrict__ csr,
                                                    const float* __restrict__ dinv,
                                                    const float* __restrict__ bias,
                                                    float* __restrict__ out, int n) {
    int tid = threadIdx.x;
    int lane = tid & 63;
    int sl = lane & 7;
    int subbase = lane & ~7;
    int wave = tid >> 6;
    int v = blockIdx.x * 32 + wave * 8 + (lane >> 3);
    if (v >= n) return;

    float4 acc = agg32_gather(h, csr, off[v], off[v + 1], sl, subbase);

    float dv = dinv[v];
    float4 hv = *reinterpret_cast<const float4*>(h + (size_t)v * 32 + sl * 4);
    float o0 = dv * (acc.x + hv.x);
    float o1 = dv * (acc.y + hv.y);
    float o2 = dv * (acc.z + hv.z);
    float o3 = dv * (acc.w + hv.w);
    if constexpr (BR) {
        float4 b = *reinterpret_cast<const float4*>(bias + sl * 4);
        o0 = fmaxf(o0 + b.x, 0.f);
        o1 = fmaxf(o1 + b.y, 0.f);
        o2 = fmaxf(o2 + b.z, 0.f);
        o3 = fmaxf(o3 + b.w, 0.f);
    }
    if constexpr (PS) {
        o0 *= dv; o1 *= dv; o2 *= dv; o3 *= dv;
    }
    *reinterpret_cast<float4*>(out + (size_t)v * 32 + sl * 4) = float4{o0, o1, o2, o3};
}

// ---------------------------------------------------------------------------
// agg32mm: agg32 (+b, relu, *dv) FUSED with @W (32x32) -> out = (D.x3)@W4.
// W staged in 4KB LDS; per node: 32 shfl broadcasts + 32 float4 FMAs,
// hidden under the latency-bound gather. Output row-major [N][32].
// ---------------------------------------------------------------------------
__global__ __launch_bounds__(256) void agg32mm_kernel(const float* __restrict__ h,
                                                      const int* __restrict__ off,
                                                      const int* __restrict__ csr,
                                                      const float* __restrict__ dinv,
                                                      const float* __restrict__ bias,
                                                      const float* __restrict__ W,
                                                      float* __restrict__ out, int n) {
    __shared__ float Ws[32 * 32];
    int tid = threadIdx.x;
    *reinterpret_cast<float4*>(&Ws[tid * 4]) =
        *reinterpret_cast<const float4*>(W + tid * 4);
    __syncthreads();

    int lane = tid & 63;
    int sl = lane & 7;
    int subbase = lane & ~7;
    int wave = tid >> 6;
    int v = blockIdx.x * 32 + wave * 8 + (lane >> 3);
    if (v >= n) return;

    float4 acc = agg32_gather(h, csr, off[v], off[v + 1], sl, subbase);

    float dv = dinv[v];
    float4 hv = *reinterpret_cast<const float4*>(h + (size_t)v * 32 + sl * 4);
    float4 b = *reinterpret_cast<const float4*>(bias + sl * 4);
    float o0 = fmaxf(dv * (acc.x + hv.x) + b.x, 0.f) * dv;
    float o1 = fmaxf(dv * (acc.y + hv.y) + b.y, 0.f) * dv;
    float o2 = fmaxf(dv * (acc.z + hv.z) + b.z, 0.f) * dv;
    float o3 = fmaxf(dv * (acc.w + hv.w) + b.w, 0.f) * dv;

    // y[4sl..4sl+3] = sum_k x[k] * W[k][4sl..]; x[k] broadcast via shfl.
    float y0 = 0.f, y1 = 0.f, y2 = 0.f, y3 = 0.f;
#pragma unroll
    for (int q = 0; q < 8; q++) {
        float x0 = __shfl(o0, subbase + q);
        float x1 = __shfl(o1, subbase + q);
        float x2 = __shfl(o2, subbase + q);
        float x3 = __shfl(o3, subbase + q);
        float4 w0 = *reinterpret_cast<const float4*>(&Ws[(4 * q + 0) * 32 + sl * 4]);
        float4 w1 = *reinterpret_cast<const float4*>(&Ws[(4 * q + 1) * 32 + sl * 4]);
        float4 w2 = *reinterpret_cast<const float4*>(&Ws[(4 * q + 2) * 32 + sl * 4]);
        float4 w3 = *reinterpret_cast<const float4*>(&Ws[(4 * q + 3) * 32 + sl * 4]);
        y0 += x0 * w0.x + x1 * w1.x + x2 * w2.x + x3 * w3.x;
        y1 += x0 * w0.y + x1 * w1.y + x2 * w2.y + x3 * w3.y;
        y2 += x0 * w0.z + x1 * w1.z + x2 * w2.z + x3 * w3.z;
        y3 += x0 * w0.w + x1 * w1.w + x2 * w2.w + x3 * w3.w;
    }
    *reinterpret_cast<float4*>(out + (size_t)v * 32 + sl * 4) = float4{y0, y1, y2, y3};
}

// ---------------------------------------------------------------------------
// agg32fin: raw agg32 FUSED with (t@W5+b5).relu @ Wl + bl -> out[v] scalar.
// W5 (8KB), b5, wl staged in LDS; lane owns 8 of 64 mid-cols; 8-lane
// shfl-xor reduce; lane0-of-8 writes.
// ---------------------------------------------------------------------------
__global__ __launch_bounds__(256) void agg32fin_kernel(const float* __restrict__ h,
                                                       const int* __restrict__ off,
                                                       const int* __restrict__ csr,
                                                       const float* __restrict__ dinv,
                                                       const float* __restrict__ W5,
                                                       const float* __restrict__ b5,
                                                       const float* __restrict__ Wl,
                                                       const float* __restrict__ bl,
                                                       float* __restrict__ out, int n) {
    __shared__ float W5s[32 * 64];
    __shared__ float b5s[64];
    __shared__ float wls[64];
    int tid = threadIdx.x;
    *reinterpret_cast<float4*>(&W5s[tid * 8]) =
        *reinterpret_cast<const float4*>(W5 + tid * 8);
    *reinterpret_cast<float4*>(&W5s[tid * 8 + 4]) =
        *reinterpret_cast<const float4*>(W5 + tid * 8 + 4);
    if (tid < 64) b5s[tid] = b5[tid];
    else if (tid < 128) wls[tid - 64] = Wl[tid - 64];
    __syncthreads();

    int lane = tid & 63;
    int sl = lane & 7;
    int subbase = lane & ~7;
    int wave = tid >> 6;
    int v = blockIdx.x * 32 + wave * 8 + (lane >> 3);
    if (v >= n) return;

    float4 acc = agg32_gather(h, csr, off[v], off[v + 1], sl, subbase);

    float dv = dinv[v];
    float4 hv = *reinterpret_cast<const float4*>(h + (size_t)v * 32 + sl * 4);
    float t0 = dv * (acc.x + hv.x);
    float t1 = dv * (acc.y + hv.y);
    float t2 = dv * (acc.z + hv.z);
    float t3 = dv * (acc.w + hv.w);

    // y[sl*8 .. sl*8+7] = sum_k t[k] * W5[k][sl*8..]
    float y0 = 0.f, y1 = 0.f, y2 = 0.f, y3 = 0.f;
    float y4 = 0.f, y5 = 0.f, y6 = 0.f, y7 = 0.f;
#pragma unroll
    for (int q = 0; q < 8; q++) {
        float x0 = __shfl(t0, subbase + q);
        float x1 = __shfl(t1, subbase + q);
        float x2 = __shfl(t2, subbase + q);
        float x3 = __shfl(t3, subbase + q);
#pragma unroll
        for (int r = 0; r < 4; r++) {
            float xv = (r == 0) ? x0 : (r == 1) ? x1 : (r == 2) ? x2 : x3;
            const float* wr = &W5s[(4 * q + r) * 64 + sl * 8];
            float4 wa = *reinterpret_cast<const float4*>(wr);
            float4 wb = *reinterpret_cast<const float4*>(wr + 4);
            y0 += xv * wa.x; y1 += xv * wa.y; y2 += xv * wa.z; y3 += xv * wa.w;
            y4 += xv * wb.x; y5 += xv * wb.y; y6 += xv * wb.z; y7 += xv * wb.w;
        }
    }
    float4 ba = *reinterpret_cast<const float4*>(&b5s[sl * 8]);
    float4 bb = *reinterpret_cast<const float4*>(&b5s[sl * 8 + 4]);
    float4 wa = *reinterpret_cast<const float4*>(&wls[sl * 8]);
    float4 wb = *reinterpret_cast<const float4*>(&wls[sl * 8 + 4]);
    float z = fmaxf(y0 + ba.x, 0.f) * wa.x + fmaxf(y1 + ba.y, 0.f) * wa.y +
              fmaxf(y2 + ba.z, 0.f) * wa.z + fmaxf(y3 + ba.w, 0.f) * wa.w +
              fmaxf(y4 + bb.x, 0.f) * wb.x + fmaxf(y5 + bb.y, 0.f) * wb.y +
              fmaxf(y6 + bb.z, 0.f) * wb.z + fmaxf(y7 + bb.w, 0.f) * wb.w;
    z += __shfl_xor(z, 4);
    z += __shfl_xor(z, 2);
    z += __shfl_xor(z, 1);
    if (sl == 0) out[v] = z + bl[0];
}

// ---------------------------------------------------------------------------
// Register-tiled GEMM: h[N,F] = x[N,K] @ W[K,F]; epilogue +bias/relu (BR),
// *dinv[row] (PS). KC=32 (KCP=36 breaks pow-2 banks).
// CIN/COUT: 0 = row-major, 32 = chunk-major [F/32][N][32] (for agg128x).
// ---------------------------------------------------------------------------
template <int K, int F, bool BR, bool PS, int CIN = 0, int COUT = 0>
__global__ __launch_bounds__(256, 4) void gemm_tiled(const float* __restrict__ x,
                                                     const float* __restrict__ W,
                                                     const float* __restrict__ bias,
                                                     const float* __restrict__ dinv,
                                                     float* __restrict__ h, int n) {
    constexpr int KC = 32;
    constexpr int KCP = 36;             // padded row stride (144 B, 16B-aligned)
    constexpr int ROWS = 64;
    constexpr int TPC = F / 4;
    constexpr int RT = 256 / TPC;
    constexpr int RPT = ROWS / RT;
    static_assert(K % KC == 0, "K must be a multiple of 32");

    __shared__ float Ws[KC * F];
    __shared__ float Xs[ROWS * KCP];

    const int tid = threadIdx.x;
    const int cb = (tid % TPC) * 4;
    const int tr = tid / TPC;
    const int row0 = blockIdx.x * ROWS;

    float acc[RPT][4];
#pragma unroll
    for (int r = 0; r < RPT; r++)
#pragma unroll
        for (int j = 0; j < 4; j++) acc[r][j] = 0.f;

#pragma unroll 1
    for (int k0 = 0; k0 < K; k0 += KC) {
        __syncthreads();
        {
            int r = tid >> 2;
            int kk = (tid & 3) * 8;
            int gr = row0 + r;
            float4 v0 = {0.f, 0.f, 0.f, 0.f}, v1 = {0.f, 0.f, 0.f, 0.f};
            if (gr < n) {
                if constexpr (CIN == 32) {
                    const float* xb = x + (size_t)(k0 >> 5) * n * 32 + (size_t)gr * 32 + kk;
                    v0 = *reinterpret_cast<const float4*>(xb);
                    v1 = *reinterpret_cast<const float4*>(xb + 4);
                } else {
                    v0 = *reinterpret_cast<const float4*>(x + (size_t)gr * K + k0 + kk);
                    v1 = *reinterpret_cast<const float4*>(x + (size_t)gr * K + k0 + kk + 4);
                }
            }
            *reinterpret_cast<float4*>(&Xs[r * KCP + kk]) = v0;
            *reinterpret_cast<float4*>(&Xs[r * KCP + kk + 4]) = v1;
        }
        for (int i = tid; i < KC * F / 4; i += 256) {
            *reinterpret_cast<float4*>(&Ws[i * 4]) =
                *reinterpret_cast<const float4*>(W + (size_t)k0 * F + i * 4);
        }
        __syncthreads();

#pragma unroll 4
        for (int kk4 = 0; kk4 < KC; kk4 += 4) {
            float4 xr[RPT];
#pragma unroll
            for (int r = 0; r < RPT; r++)
                xr[r] = *reinterpret_cast<const float4*>(&Xs[(tr * RPT + r) * KCP + kk4]);
#pragma unroll
            for (int j = 0; j < 4; j++) {
                float4 w = *reinterpret_cast<const float4*>(&Ws[(kk4 + j) * F + cb]);
#pragma unroll
                for (int r = 0; r < RPT; r++) {
                    float xv = (j == 0) ? xr[r].x : (j == 1) ? xr[r].y
                             : (j == 2) ? xr[r].z : xr[r].w;
                    acc[r][0] += xv * w.x;
                    acc[r][1] += xv * w.y;
                    acc[r][2] += xv * w.z;
                    acc[r][3] += xv * w.w;
                }
            }
        }
    }

    float4 b = float4{0.f, 0.f, 0.f, 0.f};
    if constexpr (BR) b = *reinterpret_cast<const float4*>(bias + cb);
#pragma unroll
    for (int r = 0; r < RPT; r++) {
        int row = row0 + tr * RPT + r;
        if (row < n) {
            float o0 = acc[r][0], o1 = acc[r][1], o2 = acc[r][2], o3 = acc[r][3];
            if constexpr (BR) {
                o0 = fmaxf(o0 + b.x, 0.f);
                o1 = fmaxf(o1 + b.y, 0.f);
                o2 = fmaxf(o2 + b.z, 0.f);
                o3 = fmaxf(o3 + b.w, 0.f);
            }
            if constexpr (PS) {
                float dv = dinv[row];
                o0 *= dv; o1 *= dv; o2 *= dv; o3 *= dv;
            }
            if constexpr (COUT == 32) {
                float* hb = h + (size_t)(cb >> 5) * n * 32 + (size_t)row * 32 + (cb & 31);
                *reinterpret_cast<float4*>(hb) = float4{o0, o1, o2, o3};
            } else {
                *reinterpret_cast<float4*>(&h[(size_t)row * F + cb]) = float4{o0, o1, o2, o3};
            }
        }
    }
}

// Simple GEMM for K=2 (layer 1), epilogue +bias/relu (BR), *dinv (PS).
template <int K, int F, bool BR, bool PS>
__global__ __launch_bounds__(256, 4) void gemm_small(const float* __restrict__ x,
                                                     const float* __restrict__ W,
                                                     const float* __restrict__ bias,
                                                     const float* __restrict__ dinv,
                                                     float* __restrict__ h, int n) {
    constexpr int TPR = F / 4;
    constexpr int ROWS = 256 / TPR;
    __shared__ float Ws[K * F];
    for (int i = threadIdx.x; i < K * F; i += 256) Ws[i] = W[i];
    __syncthreads();

    int tid = threadIdx.x;
    int cb = (tid % TPR) * 4;
    int r = blockIdx.x * ROWS + tid / TPR;
    if (r >= n) return;

    const float* xr = x + (size_t)r * K;
    float a0 = 0.f, a1 = 0.f, a2 = 0.f, a3 = 0.f;
#pragma unroll
    for (int k = 0; k < K; k++) {
        float xv = xr[k];
        float4 w = *reinterpret_cast<const float4*>(&Ws[k * F + cb]);
        a0 += xv * w.x; a1 += xv * w.y; a2 += xv * w.z; a3 += xv * w.w;
    }
    if constexpr (BR) {
        float4 b = *reinterpret_cast<const float4*>(bias + cb);
        a0 = fmaxf(a0 + b.x, 0.f);
        a1 = fmaxf(a1 + b.y, 0.f);
        a2 = fmaxf(a2 + b.z, 0.f);
        a3 = fmaxf(a3 + b.w, 0.f);
    }
    if constexpr (PS) {
        float dv = dinv[r];
        a0 *= dv; a1 *= dv; a2 *= dv; a3 *= dv;
    }
    *reinterpret_cast<float4*>(&h[(size_t)r * F + cb]) = float4{a0, a1, a2, a3};
}

extern "C" void kernel_launch(void* const* d_in, const int* in_sizes, int n_in,
                              void* d_out, int out_size, void* d_ws, size_t ws_size,
                              hipStream_t stream) {
    const float* x = (const float*)d_in[0];
    const int* ei = (const int*)d_in[1];
    const float* W1 = (const float*)d_in[3];
    const float* b1 = (const float*)d_in[4];
    const float* W2 = (const float*)d_in[5];
    const float* b2 = (const float*)d_in[6];
    const float* W3 = (const float*)d_in[7];
    const float* b3 = (const float*)d_in[8];
    const float* W4 = (const float*)d_in[9];
    const float* b4 = (const float*)d_in[10];
    const float* W5 = (const float*)d_in[11];
    const float* b5 = (const float*)d_in[12];
    const float* Wl = (const float*)d_in[13];
    const float* bl = (const float*)d_in[14];

    const int N = in_sizes[0] / 2;
    const int E = in_sizes[1] / 2;
    const int* src = ei;
    const int* dst = ei + E;

    char* wp = (char*)d_ws;
    auto alloc = [&](size_t bytes) -> void* {
        void* p = wp;
        wp += ((bytes + 255) / 256) * 256;
        return p;
    };
    int* cntq = (int*)alloc((size_t)N * 4 * 4);
    int* off = (int*)alloc((size_t)(N + 1) * 4);
    int* cursorq = (int*)alloc((size_t)N * 4 * 4);
    int* bsum = (int*)alloc(512 * 4);
    int* bpre = (int*)alloc(512 * 4);
    int* csr = (int*)alloc((size_t)E * 4);
    float* dinv = (float*)alloc((size_t)N * 4);
    float* xs2 = (float*)alloc((size_t)N * 2 * 4);
    float* t2 = (float*)alloc((size_t)N * 2 * 4);
    float* bufA = (float*)alloc((size_t)N * 128 * 4);
    float* bufB = (float*)alloc((size_t)N * 128 * 4);

    const int gN = cdiv(N, 256);
    const int gE = cdiv(E, 256);
    const int nb = gN;
    const int gT = cdiv(N, 64);
    const int q1 = (N + 3) / 4;         // src quartile width

    // Ranged fill grid: 8 classes x 128 chunks.
    const int NCHUNK = 128;
    const int echunk = cdiv(E, NCHUNK);
    const int gR = 8 * NCHUNK;

    // agg128x grid: 8 classes (4 chunks x 2 dst-halves) x node-groups of 32.
    const int gX = 8 * cdiv((N + 1) / 2, 32);
    const int gA = cdiv(N, 32);

    // --- CSR build (src-quartile-bucketed edge order) ---
    zero_i32<<<cdiv(4 * N, 256), 256, 0, stream>>>(cntq, 4 * N);
    count_q<<<gE, 256, 0, stream>>>(src, dst, cntq, E, q1);
    scan1q<<<nb, 256, 0, stream>>>(cntq, off, bsum, N);
    scan2<<<1, 512, 0, stream>>>(bsum, bpre, nb, off, N, E);
    scan3_fused<<<nb, 256, 0, stream>>>(cntq, bpre, off, cursorq, x, dinv, xs2, N);
    fill_ranged<<<gR, 256, 0, stream>>>(src, dst, cursorq, csr, E, N, echunk, q1);

    // --- Layer 1: agg pre-scaled [N,2], gemm 2->128 (+b1, relu, *dinv) ---
    agg2_kernel<<<gN, 256, 0, stream>>>(xs2, off, csr, dinv, t2, N);
    gemm_small<2, 128, true, true><<<cdiv(N, 8), 256, 0, stream>>>(t2, W1, b1, dinv, bufA, N);
    // --- Layer 2: gemm 128->128 (raw, cm32 out), agg128x (+b2, relu, *dinv) ---
    gemm_tiled<128, 128, false, false, 0, 32><<<gT, 256, 0, stream>>>(bufA, W2, nullptr, nullptr, bufB, N);
    agg128x_kernel<true, true><<<gX, 256, 0, stream>>>(bufB, off, csr, dinv, b2, bufA, N);
    // --- Layer 3: gemm 128->32 (cm32 in), agg32mm (+b3, relu, *dinv, @W4) ---
    gemm_tiled<128, 32, false, false, 32, 0><<<gT, 256, 0, stream>>>(bufA, W3, nullptr, nullptr, bufB, N);
    agg32mm_kernel<<<gA, 256, 0, stream>>>(bufB, off, csr, dinv, b3, W4, bufA, N);
    // --- Layer 4: agg32 (+b4, relu, *dinv) -> D.x4 ---
    agg32_kernel<true, true><<<gA, 256, 0, stream>>>(bufA, off, csr, dinv, b4, bufB, N);
    // --- Layer 5: fused raw agg + (t@W5+b5).relu @ Wl + bl -> out ---
    agg32fin_kernel<<<gA, 256, 0, stream>>>(bufB, off, csr, dinv, W5, b5, Wl, bl, (float*)d_out, N);
}